// Round 9
// baseline (1809.552 us; speedup 1.0000x reference)
//
#include <hip/hip_runtime.h>
#include <hip/hip_bf16.h>

typedef unsigned short u16;   // bf16 bits
typedef __attribute__((ext_vector_type(8))) short bf16x8;   // MFMA A/B frag
typedef __attribute__((ext_vector_type(4))) float f32x4;    // MFMA C/D frag

#define B_   32
#define N_   1024
#define E_   16384
#define ET_  17408            // E_ + N_ self-loops
#define IN_DIM 768
#define HID  512
#define OUT_ 400
#define PAIR_ 800
#define UVW_ 1600             // U(800) ++ V(800) per node
#define FEAT_ELEMS 13107200   // B_*N_*OUT_
#define MAXD 128

__device__ __forceinline__ float u2f(u16 u) {
    union { unsigned int i; float f; } v; v.i = ((unsigned int)u) << 16; return v.f;
}
__device__ __forceinline__ u16 f2u(float f) {
    __hip_bfloat16 h = __float2bfloat16(f);   // RNE, HW cvt on gfx950
    return *(u16*)&h;
}
__device__ __forceinline__ unsigned int pack2(float a, float b) {
    return (unsigned int)f2u(a) | ((unsigned int)f2u(b) << 16);
}

__device__ __forceinline__ float gelu_f(float x) {
    const float c = 0.7978845608028654f;          // sqrt(2/pi)
    float u = c * (x + 0.044715f * x * x * x);
    float t = 2.0f / (1.0f + __expf(-2.0f * u)) - 1.0f;   // tanh(u), overflow-safe
    return 0.5f * x * (1.0f + t);
}

// async global->LDS, 16 B per lane; LDS dest is wave-uniform base + lane*16
__device__ __forceinline__ void load_lds16(const void* g, void* l) {
    __builtin_amdgcn_global_load_lds(
        (const __attribute__((address_space(1))) void*)g,
        (__attribute__((address_space(3))) void*)l, 16, 0, 0);
}

// ---------------------------------------------------------------------------
// Weight transpose + bf16 convert: Wt[n][k] = bf16(W[k][n]). Tiny, once/launch.
// ---------------------------------------------------------------------------
__global__ void wt_k(const float* __restrict__ W, u16* __restrict__ Wt,
                     int K, int N)
{
    int i = blockIdx.x * 256 + threadIdx.x;
    if (i >= N * K) return;
    int n = i / K, k = i - n * K;
    Wt[i] = f2u(W[(size_t)k * N + n]);
}

// h_w1 [800][800] -> uvwt [1600][400] bf16 (transposed, halves split)
__global__ void wtuv_k(const float* __restrict__ W, u16* __restrict__ Wt)
{
    int i = blockIdx.x * 256 + threadIdx.x;       // over 1600*400
    if (i >= UVW_ * OUT_) return;
    int n = i / OUT_, k = i - n * OUT_;
    int row = (n >= PAIR_) ? OUT_ + k : k;
    int col = (n >= PAIR_) ? n - PAIR_ : n;
    Wt[i] = f2u(W[(size_t)row * PAIR_ + col]);
}

// f32 -> bf16 bulk convert, 8 elems/lane
__global__ void f2b_k(const float* __restrict__ X, u16* __restrict__ Y, int n8)
{
    int i = blockIdx.x * 256 + threadIdx.x;
    if (i >= n8) return;
    const float4* p = (const float4*)X + (size_t)i * 2;
    float4 a = p[0], b = p[1];
    uint4 o;
    o.x = pack2(a.x, a.y); o.y = pack2(a.z, a.w);
    o.z = pack2(b.x, b.y); o.w = pack2(b.z, b.w);
    ((uint4*)Y)[i] = o;
}

// ---------------------------------------------------------------------------
// MFMA GEMM: C[M,N] = act(A[M,K] @ W[K,N] + bias), f32 accumulate.
// SHAPE 0: 128x128, BK=64, 4 waves (small-mode legacy; ASRC 0/1)
// SHAPE 1: 256x256, BK=64, 8 waves, wave=64x128, LDS 128KB dbuf.
// ASRC: 0 = f32 A (VGPR cvt staging, SHAPE0 only)
//       1 = bf16 A (async global_load_lds)
//       2 = GATHER-GELU A (SHAPE1): A row r = gelu(UV[src][k]+UV[dst][800+k]
//           +b1[k]) built in-register and ds_written swizzled. Eliminates the
//           p1 materialization — r4-r7 showed head GEMM2 was bound by the p1
//           HBM round-trip (chunk time == FETCH/~550GB/s in every config).
//           UV (105MB) is L3-resident; gelu VALU hides under MFMA (m114).
//           Af carries b1. SWIZZLE DISCIPLINE (rule #21, r8 bug): A-side
//           ds_write applies the XOR explicitly (pc = chunk^(r&7)) so its
//           global loads use LOGICAL chunk (lane&7); B-side global_load_lds
//           writes LINEARLY so its global load must use PRE-SWIZZLED chunk
//           cl = (lane&7)^(lane>>3) — r8 wrongly reused (lane&7) for B.
//           Sync: UV-data use inside stage() drains all earlier VMEM
//           (in-order vmcnt) incl. current tile's B; pre-barrier
//           s_waitcnt vmcnt(4) lgkmcnt(0) keeps next-tile B in flight.
// 2-phase pipeline: stage(next) BEFORE compute; counted vmcnt; raw s_barrier.
// T1 XCD-chunked bijective swizzle (m204) for L2 locality of A panels.
// FUSE_H3: no C store; contract tile with w3 [N][3] after gelu(.+bias):
// shfl over lm, LDS-combine CW col-waves, non-atomic part[bnIdx][row][3];
// red3_k sums gx slices + b3 (r3 atomic version was 48MB write-through).
// ---------------------------------------------------------------------------
template<int ASRC, bool DO_GELU, bool HAS_BIAS, bool OUT_F32, bool FUSE_H3, int SHAPE>
__global__ __launch_bounds__(SHAPE >= 1 ? 512 : 256, 2)
void mfma_gemm_k(const float* __restrict__ Af, const u16* __restrict__ Ab,
                 const u16* __restrict__ Wt, const float* __restrict__ bias,
                 u16* __restrict__ Cb, float* __restrict__ Cf,
                 int M, int N, int K,
                 const u16* __restrict__ zbuf,
                 const float* __restrict__ w3p, float* __restrict__ partp,
                 const int* __restrict__ src0p, const int* __restrict__ dst0p,
                 int b0)
{
    static_assert(SHAPE == 0 || ASRC >= 1, "wide shapes need bf16/gather staging");
    constexpr int BM  = (SHAPE == 1) ? 256 : 128;
    constexpr int BN  = (SHAPE == 1) ? 256 : 128;
    constexpr int UN  = (SHAPE == 1) ? 8 : 4;      // 16-col frags per wave
    constexpr int CW  = 2;                         // col-waves per row-group

    __shared__ __align__(16) u16 As[2][BM * 64];
    __shared__ __align__(16) u16 Bs[2][BN * 64];
    const int tid  = threadIdx.x;
    // --- T1 bijective XCD swizzle ---
    const int gx   = gridDim.x;
    const int nwg  = gx * gridDim.y;
    const int orig = blockIdx.y * gx + blockIdx.x;
    const int qc   = nwg >> 3, rc = nwg & 7;
    const int xcd  = orig & 7, lid = orig >> 3;
    const int wg   = ((xcd < rc) ? xcd * (qc + 1) : rc * (qc + 1) + (xcd - rc) * qc) + lid;
    const int bnIdx= wg % gx;
    const int bm   = (wg / gx) * BM;
    const int bn   = bnIdx * BN;
    const int wave = tid >> 6;
    const int lane = tid & 63;
    const int wm   = (wave >> 1) * 64;
    const int wn   = (SHAPE == 1) ? (wave & 1) * 128 : (wave & 1) * 64;
    const int lm   = lane & 15;
    const int lq   = lane >> 4;
    const int lb   = lm & 7;
    // staging lane geometry: instr c4 covers rows wave*32+c4*8 .. +7
    const int l8 = lane >> 3;            // row within 8-row group
    const int cl = (lane & 7) ^ l8;      // PRE-SWIZZLED chunk (linear LDS dest)

    // per-c4 row metadata (wave*32 row groups cover BM rows)
    size_t arow[4]; size_t brow[4]; bool bok[4];
    #pragma unroll
    for (int c4 = 0; c4 < 4; ++c4) {
        int rt = wave * 32 + c4 * 8 + l8;          // tile row
        if (ASRC == 1) arow[c4] = (size_t)(bm + rt) * K;
        int n = bn + rt;
        bok[c4] = (n < N);
        brow[c4] = (size_t)(n < N ? n : 0) * K;
    }
    // gather-gelu row metadata (ASRC 2): per thread 4 rows (chunk col = lane&7)
    int gsv[4], gdv[4];
    if (ASRC == 2) {
        #pragma unroll
        for (int c = 0; c < 4; ++c) {
            int gr = bm + wave * 32 + c * 8 + (lane >> 3);
            int e  = gr & (E_ - 1);
            int b  = b0 + (gr >> 14);
            gsv[c] = (b << 10) + src0p[e];
            gdv[c] = (b << 10) + dst0p[e];
        }
    }
    // VGPR-staging geometry (ASRC 0, SHAPE 0 only)
    const int vrow = tid >> 1, vhalf = tid & 1;

    f32x4 acc[4][UN] = {};
    const int NT = (K + 63) >> 6;

    if (ASRC >= 1) {
        auto stage = [&](int buf, int k0) {
            if (ASRC == 2) {
                int kk  = k0 + (lane & 7) * 8;   // LOGICAL chunk (ds_write swizzles)
                int kkb = k0 + cl * 8;           // PRE-SWIZZLED (linear gload_lds)
                bool okk = (kk < PAIR_);
                uint4 qu[4], qv[4];
                float4 bA = make_float4(0, 0, 0, 0), bB = bA;
                if (okk) {
                    bA = *(const float4*)(Af + kk);       // b1 bias
                    bB = *(const float4*)(Af + kk + 4);
                    #pragma unroll
                    for (int c = 0; c < 4; ++c) {
                        qu[c] = *(const uint4*)(Ab + (size_t)gsv[c] * UVW_ + kk);
                        qv[c] = *(const uint4*)(Ab + (size_t)gdv[c] * UVW_ + PAIR_ + kk);
                    }
                }
                // B async AFTER UV issue: B stays youngest VMEM -> vmcnt(4) ok
                #pragma unroll
                for (int c4 = 0; c4 < 4; ++c4) {
                    const u16* gb = (bok[c4] && kkb < K) ? Wt + brow[c4] + kkb : zbuf;
                    load_lds16(gb, (char*)Bs[buf] + (wave * 32 + c4 * 8) * 128);
                }
                float bb[8] = {bA.x, bA.y, bA.z, bA.w, bB.x, bB.y, bB.z, bB.w};
                #pragma unroll
                for (int c = 0; c < 4; ++c) {
                    int r = wave * 32 + c * 8 + (lane >> 3);
                    uint4 wv = make_uint4(0, 0, 0, 0);
                    if (okk) {
                        unsigned uu[4] = {qu[c].x, qu[c].y, qu[c].z, qu[c].w};
                        unsigned vv[4] = {qv[c].x, qv[c].y, qv[c].z, qv[c].w};
                        unsigned* op = (unsigned*)&wv;
                        #pragma unroll
                        for (int q = 0; q < 4; ++q) {
                            float a0 = u2f((u16)(uu[q] & 0xffff)) +
                                       u2f((u16)(vv[q] & 0xffff)) + bb[2 * q];
                            float a1 = u2f((u16)(uu[q] >> 16)) +
                                       u2f((u16)(vv[q] >> 16)) + bb[2 * q + 1];
                            op[q] = pack2(gelu_f(a0), gelu_f(a1));
                        }
                    }
                    int pc = (lane & 7) ^ (r & 7);
                    *(uint4*)((char*)As[buf] + r * 128 + pc * 16) = wv;
                }
            } else {
                int kk = k0 + cl * 8;
                #pragma unroll
                for (int c4 = 0; c4 < 4; ++c4) {
                    const u16* ga = (kk < K) ? Ab + arow[c4] + kk : zbuf;
                    load_lds16(ga, (char*)As[buf] + (wave * 32 + c4 * 8) * 128);
                }
                #pragma unroll
                for (int c4 = 0; c4 < 4; ++c4) {
                    const u16* gb = (bok[c4] && kk < K) ? Wt + brow[c4] + kk : zbuf;
                    load_lds16(gb, (char*)Bs[buf] + (wave * 32 + c4 * 8) * 128);
                }
            }
        };
        stage(0, 0);
        int cur = 0;
        for (int it = 0; it < NT; ++it) {
            const bool last = (it == NT - 1);
            if (!last) stage(cur ^ 1, (it + 1) * 64);
            if (!last) {
                if (ASRC == 2) asm volatile("s_waitcnt vmcnt(4) lgkmcnt(0)" ::: "memory");
                else           asm volatile("s_waitcnt vmcnt(8)" ::: "memory");
            } else {
                asm volatile("s_waitcnt vmcnt(0) lgkmcnt(0)" ::: "memory");
            }
            __builtin_amdgcn_s_barrier();
            const char* Abase = (const char*)As[cur];
            const char* Bbase = (const char*)Bs[cur];
            #pragma unroll
            for (int kh = 0; kh < 2; ++kh) {
                bf16x8 af[4], bfr[UN];
                #pragma unroll
                for (int t = 0; t < 4; ++t)
                    af[t] = *(const bf16x8*)(Abase +
                            (wm + t * 16 + lm) * 128 + (((kh * 4 + lq) ^ lb) * 16));
                #pragma unroll
                for (int u = 0; u < UN; ++u)
                    bfr[u] = *(const bf16x8*)(Bbase +
                            (wn + u * 16 + lm) * 128 + (((kh * 4 + lq) ^ lb) * 16));
                #pragma unroll
                for (int t = 0; t < 4; ++t)
                    #pragma unroll
                    for (int u = 0; u < UN; ++u)
                        acc[t][u] = __builtin_amdgcn_mfma_f32_16x16x32_bf16(
                            af[t], bfr[u], acc[t][u], 0, 0, 0);
            }
            asm volatile("" ::: "memory");
            __builtin_amdgcn_s_barrier();
            cur ^= 1;
        }
    } else {
        for (int k0 = 0; k0 < K; k0 += 64) {
            // ---- stage A (VGPR cvt, SHAPE0 only)
            #pragma unroll
            for (int c = 0; c < 4; ++c) {
                int c_log = vhalf * 4 + c;
                int kk = k0 + c_log * 8;
                uint4 wv = make_uint4(0, 0, 0, 0);
                if (kk < K) {
                    const float* p = Af + (size_t)(bm + vrow) * K + kk;
                    float4 v0 = *(const float4*)p;
                    float4 v1 = *(const float4*)(p + 4);
                    wv.x = pack2(v0.x, v0.y); wv.y = pack2(v0.z, v0.w);
                    wv.z = pack2(v1.x, v1.y); wv.w = pack2(v1.z, v1.w);
                }
                int pc = c_log ^ (vrow & 7);
                *(uint4*)((char*)As[0] + vrow * 128 + pc * 16) = wv;
            }
            // ---- stage B (async)
            {
                int kk = k0 + cl * 8;
                #pragma unroll
                for (int c4 = 0; c4 < 4; ++c4) {
                    const u16* gb = (bok[c4] && kk < K) ? Wt + brow[c4] + kk : zbuf;
                    load_lds16(gb, (char*)Bs[0] + (wave * 32 + c4 * 8) * 128);
                }
            }
            __syncthreads();
            #pragma unroll
            for (int kh = 0; kh < 2; ++kh) {
                bf16x8 af[4], bfr[UN];
                #pragma unroll
                for (int t = 0; t < 4; ++t)
                    af[t] = *(const bf16x8*)((const char*)As[0] +
                            (wm + t * 16 + lm) * 128 + (((kh * 4 + lq) ^ lb) * 16));
                #pragma unroll
                for (int u = 0; u < UN; ++u)
                    bfr[u] = *(const bf16x8*)((const char*)Bs[0] +
                            (wn + u * 16 + lm) * 128 + (((kh * 4 + lq) ^ lb) * 16));
                #pragma unroll
                for (int t = 0; t < 4; ++t)
                    #pragma unroll
                    for (int u = 0; u < UN; ++u)
                        acc[t][u] = __builtin_amdgcn_mfma_f32_16x16x32_bf16(
                            af[t], bfr[u], acc[t][u], 0, 0, 0);
            }
            __syncthreads();
        }
    }

    // ---- fused head3 epilogue: part[bnIdx][row] = gelu(p2_tile) @ w3
    if (FUSE_H3) {
        float w3c[UN][3]; float bvv[UN];
        #pragma unroll
        for (int u = 0; u < UN; ++u) {
            int col = bn + wn + u * 16 + lm;
            bool ok = (col < N);
            bvv[u]    = ok ? bias[col] : 0.f;
            w3c[u][0] = ok ? w3p[col * 3 + 0] : 0.f;
            w3c[u][1] = ok ? w3p[col * 3 + 1] : 0.f;
            w3c[u][2] = ok ? w3p[col * 3 + 2] : 0.f;
        }
        float* red = (float*)As;         // [waves][64 rows][3] floats, As dead
        #pragma unroll
        for (int t = 0; t < 4; ++t) {
            #pragma unroll
            for (int r = 0; r < 4; ++r) {
                float s0 = 0.f, s1 = 0.f, s2 = 0.f;
                #pragma unroll
                for (int u = 0; u < UN; ++u) {
                    float v = gelu_f(acc[t][u][r] + bvv[u]);
                    s0 += v * w3c[u][0];
                    s1 += v * w3c[u][1];
                    s2 += v * w3c[u][2];
                }
                #pragma unroll
                for (int off = 8; off; off >>= 1) {
                    s0 += __shfl_xor(s0, off);
                    s1 += __shfl_xor(s1, off);
                    s2 += __shfl_xor(s2, off);
                }
                if (lm == 0) {
                    int lr = t * 16 + lq * 4 + r;            // 0..63 within wave
                    float* d = red + (wave * 64 + lr) * 3;
                    d[0] = s0; d[1] = s1; d[2] = s2;
                }
            }
        }
        __syncthreads();
        if ((wave & (CW - 1)) == 0) {     // lead wave of each row-group pair
            int lr = lane;
            int rowg = bm + wm + lr;
            float s0 = 0.f, s1 = 0.f, s2 = 0.f;
            #pragma unroll
            for (int w = 0; w < CW; ++w) {
                float* a = red + ((wave + w) * 64 + lr) * 3;
                s0 += a[0]; s1 += a[1]; s2 += a[2];
            }
            float* d = partp + ((size_t)bnIdx * M + rowg) * 3;
            d[0] = s0; d[1] = s1; d[2] = s2;
        }
        return;
    }

    // ---- epilogue: C col = lane&15, row = quad*4 + reg (verified m89/m91)
    #pragma unroll
    for (int u = 0; u < UN; ++u) {
        int col = bn + wn + u * 16 + lm;
        if (col >= N) continue;
        float bv = HAS_BIAS ? bias[col] : 0.f;
        #pragma unroll
        for (int t = 0; t < 4; ++t) {
            #pragma unroll
            for (int r = 0; r < 4; ++r) {
                int rowg = bm + wm + t * 16 + lq * 4 + r;
                float v = acc[t][u][r] + bv;
                if (DO_GELU) v = gelu_f(v);
                if (OUT_F32) {
                    Cf[(size_t)rowg * N + col] = v;
                    if (Cb) Cb[(size_t)rowg * N + col] = f2u(v);  // dual write
                } else {
                    Cb[(size_t)rowg * N + col] = f2u(v);
                }
            }
        }
    }
}

// ---------------------------------------------------------------------------
// Partial reduce: pred[row_base+r,:] = b3 + sum_{s<ns} part[s][r][:]
// ---------------------------------------------------------------------------
__global__ __launch_bounds__(256)
void red3_k(const float* __restrict__ part, const float* __restrict__ b3,
            float* __restrict__ out, int row_base, int Mr, int ns)
{
    int r = blockIdx.x * 256 + threadIdx.x;
    if (r >= Mr) return;
    float s0 = b3[0], s1 = b3[1], s2 = b3[2];
    for (int s = 0; s < ns; ++s) {
        const float* p = part + ((size_t)s * Mr + r) * 3;
        s0 += p[0]; s1 += p[1]; s2 += p[2];
    }
    float* d = out + (size_t)FEAT_ELEMS + (size_t)(row_base + r) * 3;
    d[0] = s0; d[1] = s1; d[2] = s2;
}

// ---------------------------------------------------------------------------
// Pair fuse (small mode only): p1[r,:] = gelu(U[src] + V[dst] + b1).
// ---------------------------------------------------------------------------
__global__ __launch_bounds__(256)
void pair_fuse_k(const u16* __restrict__ UV, const float* __restrict__ b1,
                 const int* __restrict__ src0, const int* __restrict__ dst0,
                 u16* __restrict__ p1, int b0, int nrows)
{
    unsigned idx = blockIdx.x * 256u + threadIdx.x;
    unsigned total = (unsigned)nrows * 100u;
    if (idx >= total) return;
    unsigned r  = (unsigned)(((unsigned long long)idx * 1374389535ull) >> 37); // /100
    unsigned c8 = idx - r * 100u;
    int e = r & (E_ - 1);
    int gs, gd;
    if (b0 >= 0) {
        int b = b0 + (int)(r >> 14);
        gs = (b << 10) + src0[e];
        gd = (b << 10) + dst0[e];
    } else {
        gs = src0[e]; gd = dst0[e];
    }
    uint4 qu = *(const uint4*)(UV + (size_t)gs * UVW_ + c8 * 8);
    uint4 qv = *(const uint4*)(UV + (size_t)gd * UVW_ + PAIR_ + c8 * 8);
    float4 bva = *(const float4*)(b1 + c8 * 8);
    float4 bvb = *(const float4*)(b1 + c8 * 8 + 4);
    float bb[8] = {bva.x, bva.y, bva.z, bva.w, bvb.x, bvb.y, bvb.z, bvb.w};
    unsigned int uu[4] = {qu.x, qu.y, qu.z, qu.w};
    unsigned int vv[4] = {qv.x, qv.y, qv.z, qv.w};
    uint4 o; unsigned int* op = (unsigned int*)&o;
    #pragma unroll
    for (int q = 0; q < 4; ++q) {
        float a0 = u2f((u16)(uu[q] & 0xffff)) + u2f((u16)(vv[q] & 0xffff)) + bb[2*q];
        float a1 = u2f((u16)(uu[q] >> 16))    + u2f((u16)(vv[q] >> 16))    + bb[2*q+1];
        op[q] = pack2(gelu_f(a0), gelu_f(a1));
    }
    *(uint4*)(p1 + (size_t)r * PAIR_ + c8 * 8) = o;
}

// ---------------------------------------------------------------------------
// Attention scores
// ---------------------------------------------------------------------------
__global__ __launch_bounds__(256)
void scores_k(const u16* __restrict__ wh, const float* __restrict__ att_s,
              const float* __restrict__ att_d, float* __restrict__ a_s,
              float* __restrict__ a_d)
{
    int n = blockIdx.x * 4 + (threadIdx.x >> 6);
    int lane = threadIdx.x & 63;
    const u16* row = wh + (size_t)n * OUT_;
    float as0 = 0, as1 = 0, ad0 = 0, ad1 = 0;
    for (int f = lane; f < OUT_; f += 64) {
        float v = u2f(row[f]);
        float s = att_s[f];
        float d = att_d[f];
        if (f < 200) { as0 += v * s; ad0 += v * d; }
        else         { as1 += v * s; ad1 += v * d; }
    }
    for (int off = 32; off; off >>= 1) {
        as0 += __shfl_xor(as0, off); as1 += __shfl_xor(as1, off);
        ad0 += __shfl_xor(ad0, off); ad1 += __shfl_xor(ad1, off);
    }
    if (lane == 0) {
        a_s[(size_t)n * 2 + 0] = as0; a_s[(size_t)n * 2 + 1] = as1;
        a_d[(size_t)n * 2 + 0] = ad0; a_d[(size_t)n * 2 + 1] = ad1;
    }
}

// ---------------------------------------------------------------------------
// CSR build (edges shared across batches; incl. self-loops)
// ---------------------------------------------------------------------------
__global__ void csr_count_k(const int* __restrict__ edges, int* __restrict__ deg)
{
    int et = blockIdx.x * blockDim.x + threadIdx.x;
    if (et >= ET_) return;
    int dst = (et < E_) ? edges[E_ + et] : (et - E_);
    atomicAdd(&deg[dst], 1);
}

__global__ __launch_bounds__(1024)
void csr_scan_k(const int* __restrict__ deg, int* __restrict__ row_ptr,
                int* __restrict__ cnt)
{
    __shared__ int s[1024];
    int t = threadIdx.x;
    int d = deg[t];
    s[t] = d;
    __syncthreads();
    for (int off = 1; off < 1024; off <<= 1) {
        int v = (t >= off) ? s[t - off] : 0;
        __syncthreads();
        s[t] += v;
        __syncthreads();
    }
    row_ptr[t] = s[t] - d;   // exclusive
    cnt[t] = s[t] - d;
    if (t == 1023) row_ptr[1024] = s[t];
}

__global__ void csr_fill_k(const int* __restrict__ edges, int* __restrict__ cnt,
                           int* __restrict__ col_src)
{
    int et = blockIdx.x * blockDim.x + threadIdx.x;
    if (et >= ET_) return;
    int src, dst;
    if (et < E_) { src = edges[et]; dst = edges[E_ + et]; }
    else         { src = et - E_;  dst = src; }
    int pos = atomicAdd(&cnt[dst], 1);
    col_src[pos] = src;
}

// ---------------------------------------------------------------------------
// Fused GAT softmax + aggregation + residual, in place on f32 feat (d_out).
// ---------------------------------------------------------------------------
__global__ __launch_bounds__(256)
void gat_k(const u16* __restrict__ wh,
           const float* __restrict__ a_s, const float* __restrict__ a_d,
           const int* __restrict__ row_ptr, const int* __restrict__ col_src,
           const float* __restrict__ gat_b, float* __restrict__ feat,
           u16* __restrict__ featb16)
{
    int gn = blockIdx.x;                  // b*1024 + n
    int b = gn >> 10, n = gn & 1023;
    int tid = threadIdx.x;
    __shared__ float s_ee[2][MAXD];
    __shared__ int   s_src[MAXD];
    __shared__ float s_misc[6];           // m0,m1,invz0,invz1,ad0,ad1
    __shared__ float s_part[4][50][9];    // +1 pad col: spread banks
    int start = row_ptr[n];
    int deg = row_ptr[n + 1] - start;

    if (tid < 64) {
        int lane = tid;
        float ad0 = a_d[(size_t)gn * 2 + 0];
        float ad1 = a_d[(size_t)gn * 2 + 1];
        float m0 = -1e30f, m1 = -1e30f;
        for (int j = lane; j < deg; j += 64) {
            int gs = (b << 10) + col_src[start + j];
            float e0 = a_s[(size_t)gs * 2 + 0] + ad0; e0 = (e0 > 0.f) ? e0 : 0.2f * e0;
            float e1 = a_s[(size_t)gs * 2 + 1] + ad1; e1 = (e1 > 0.f) ? e1 : 0.2f * e1;
            if (j < MAXD) { s_ee[0][j] = e0; s_ee[1][j] = e1; s_src[j] = gs; }
            m0 = fmaxf(m0, e0); m1 = fmaxf(m1, e1);
        }
        for (int off = 32; off; off >>= 1) {
            m0 = fmaxf(m0, __shfl_xor(m0, off));
            m1 = fmaxf(m1, __shfl_xor(m1, off));
        }
        float z0 = 0.f, z1 = 0.f;
        for (int j = lane; j < deg; j += 64) {
            float e0, e1;
            if (j < MAXD) { e0 = s_ee[0][j]; e1 = s_ee[1][j]; }
            else {
                int gs = (b << 10) + col_src[start + j];
                e0 = a_s[(size_t)gs * 2 + 0] + ad0; e0 = (e0 > 0.f) ? e0 : 0.2f * e0;
                e1 = a_s[(size_t)gs * 2 + 1] + ad1; e1 = (e1 > 0.f) ? e1 : 0.2f * e1;
            }
            float t0 = __expf(e0 - m0), t1 = __expf(e1 - m1);
            if (j < MAXD) { s_ee[0][j] = t0; s_ee[1][j] = t1; }
            z0 += t0; z1 += t1;
        }
        for (int off = 32; off; off >>= 1) {
            z0 += __shfl_xor(z0, off);
            z1 += __shfl_xor(z1, off);
        }
        if (lane == 0) {
            s_misc[0] = m0; s_misc[1] = m1;
            s_misc[2] = (z0 > 0.f) ? 1.f / z0 : 0.f;
            s_misc[3] = (z1 > 0.f) ? 1.f / z1 : 0.f;
            s_misc[4] = ad0; s_misc[5] = ad1;
        }
    }
    __syncthreads();

    int wv = tid >> 6, ln = tid & 63;
    if (ln < 50) {
        int h = (ln >= 25);
        float m = s_misc[h], ad = s_misc[4 + h];
        float acc[8] = {};
        for (int j = wv; j < deg; j += 4) {
            float w; int gs;
            if (j < MAXD) { w = s_ee[h][j]; gs = s_src[j]; }
            else {
                gs = (b << 10) + col_src[start + j];
                float e = a_s[(size_t)gs * 2 + h] + ad;
                e = (e > 0.f) ? e : 0.2f * e;
                w = __expf(e - m);
            }
            uint4 q = *(const uint4*)(wh + (size_t)gs * OUT_ + ln * 8);
            acc[0] += w * u2f((u16)(q.x & 0xffff));
            acc[1] += w * u2f((u16)(q.x >> 16));
            acc[2] += w * u2f((u16)(q.y & 0xffff));
            acc[3] += w * u2f((u16)(q.y >> 16));
            acc[4] += w * u2f((u16)(q.z & 0xffff));
            acc[5] += w * u2f((u16)(q.z >> 16));
            acc[6] += w * u2f((u16)(q.w & 0xffff));
            acc[7] += w * u2f((u16)(q.w >> 16));
        }
        #pragma unroll
        for (int k = 0; k < 8; ++k) s_part[wv][ln][k] = acc[k];
    }
    __syncthreads();
    if (tid < 50) {
        int h = (tid >= 25);
        float iz = s_misc[2 + h];
        size_t base = (size_t)gn * OUT_ + tid * 8;
        float4 f0 = *(const float4*)(feat + base);
        float4 f1 = *(const float4*)(feat + base + 4);
        float fv[8] = { f0.x, f0.y, f0.z, f0.w, f1.x, f1.y, f1.z, f1.w };
        float o[8];
        #pragma unroll
        for (int k = 0; k < 8; ++k) {
            float s = s_part[0][tid][k] + s_part[1][tid][k] +
                      s_part[2][tid][k] + s_part[3][tid][k];
            o[k] = fv[k] + s * iz + gat_b[tid * 8 + k];
        }
        *(float4*)(feat + base)     = make_float4(o[0], o[1], o[2], o[3]);
        *(float4*)(feat + base + 4) = make_float4(o[4], o[5], o[6], o[7]);
        if (featb16) {
            uint4 bq;
            bq.x = pack2(o[0], o[1]); bq.y = pack2(o[2], o[3]);
            bq.z = pack2(o[4], o[5]); bq.w = pack2(o[6], o[7]);
            *(uint4*)(featb16 + base) = bq;
        }
    }
}

// ---------------------------------------------------------------------------
// Final tiny GEMM (small-mode only): pred[e,:] = p2[e,:] @ w3[400,3] + b3.
// ---------------------------------------------------------------------------
__global__ __launch_bounds__(256)
void head3_k(const u16* __restrict__ p2, const float* __restrict__ w3,
             const float* __restrict__ b3, float* __restrict__ out,
             int row_base, int nrows)
{
    int wv = threadIdx.x >> 6, lane = threadIdx.x & 63;
    float w3r[24];
    if (lane < 50) {
        #pragma unroll
        for (int q = 0; q < 6; ++q) {
            float4 v = *(const float4*)(w3 + lane * 24 + q * 4);
            w3r[q * 4 + 0] = v.x; w3r[q * 4 + 1] = v.y;
            w3r[q * 4 + 2] = v.z; w3r[q * 4 + 3] = v.w;
        }
    }
    int e0 = blockIdx.x * 16 + wv * 4;
    for (int ei = 0; ei < 4; ++ei) {
        int e = e0 + ei;
        if (e >= nrows) break;
        float s0 = 0, s1 = 0, s2 = 0;
        if (lane < 50) {
            uint4 q = *(const uint4*)(p2 + (size_t)e * OUT_ + lane * 8);
            float f[8];
            f[0] = u2f((u16)(q.x & 0xffff)); f[1] = u2f((u16)(q.x >> 16));
            f[2] = u2f((u16)(q.y & 0xffff)); f[3] = u2f((u16)(q.y >> 16));
            f[4] = u2f((u16)(q.z & 0xffff)); f[5] = u2f((u16)(q.z >> 16));
            f[6] = u2f((u16)(q.w & 0xffff)); f[7] = u2f((u16)(q.w >> 16));
            #pragma unroll
            for (int k = 0; k < 8; ++k) {
                s0 += f[k] * w3r[k * 3 + 0];
                s1 += f[k] * w3r[k * 3 + 1];
                s2 += f[k] * w3r[k * 3 + 2];
            }
        }
        for (int off = 32; off; off >>= 1) {
            s0 += __shfl_xor(s0, off);
            s1 += __shfl_xor(s1, off);
            s2 += __shfl_xor(s2, off);
        }
        if (lane == 0) {
            size_t o = (size_t)FEAT_ELEMS + (size_t)(row_base + e) * 3;
            out[o + 0] = s0 + b3[0];
            out[o + 1] = s1 + b3[1];
            out[o + 2] = s2 + b3[2];
        }
    }
}

extern "C" void kernel_launch(void* const* d_in, const int* in_sizes, int n_in,
                              void* d_out, int out_size, void* d_ws, size_t ws_size,
                              hipStream_t stream)
{
    const float* patch  = (const float*)d_in[0];
    const int*   edges  = (const int*)d_in[1];
    const float* enc_w1 = (const float*)d_in[2];
    const float* enc_b1 = (const float*)d_in[3];
    const float* enc_w2 = (const float*)d_in[4];
    const float* enc_b2 = (const float*)d_in[5];
    const float* gat_w  = (const float*)d_in[6];
    const float* att_s  = (const float*)d_in[7];
    const float* att_d  = (const float*)d_in[8];
    const float* gat_b  = (const float*)d_in[9];
    const float* h_w1   = (const float*)d_in[10];
    const float* h_b1   = (const float*)d_in[11];
    const float* h_w2   = (const float*)d_in[12];
    const float* h_b2   = (const float*)d_in[13];
    const float* h_w3   = (const float*)d_in[14];
    const float* h_b3   = (const float*)d_in[15];
    float* out  = (float*)d_out;
    float* feat = out;                          // f32 [32768,400] in d_out
    char*  ws   = (char*)d_ws;

    const int* src0 = edges;
    const int* dst0 = edges + E_;

    // --- mode select from ws_size (deterministic; graph-capture safe) ------
    // big-mode layout:
    //   [0,R0)            enc1 bf16; featb16 overlays (dead enc1);
    //                     head-phase: part f32 [2][B*E][3] (12.6MB)
    //   [R0, R0+26.2MB)   whb bf16 (dead after gat_k)
    //   [R0+26.2,+52.4MB) encb16 bf16 (consumed by GAT linear)
    //   [R0, R0+UVSZ)     UV bf16 [32768,1600] (overlays whb+encb16, after gat)
    //   [R0+UVSZ, +50MB)  patchb16 (dead before head)
    //   [ws_size-TAIL,..) weights + scores + CSR + zbuf
    // p1/p2 eliminated: head GEMM1 distributed into UV, gather+gelu fused into
    // head GEMM2's A-staging (ASRC 2), head3 fused into its epilogue.
    const size_t R0 = 33554432ull, TAIL = 4194304ull;
    const size_t UVSZ = 104857600ull;           // 32768*1600*2
    const size_t P1SZ = 26214400ull;
    const bool big = (ws_size >= R0 + UVSZ + TAIL + 2 * P1SZ);

    u16 *enc1, *whb, *p1, *p2, *featb16, *uv, *w1t, *w2t, *gwt, *uvwt, *hw2t;
    u16 *patchb16, *encb16;
    float *a_s, *a_d, *part; int *deg;
    if (big) {
        enc1    = (u16*)ws;
        featb16 = (u16*)ws;                     // overlays enc1 (dead)
        part    = (float*)ws;                   // head-phase reuse (featb16 dead)
        whb     = (u16*)(ws + R0);
        uv      = (u16*)(ws + R0);              // overlays whb (dead after gat)
        encb16  = (u16*)(ws + R0 + 26214400ull);// enc bf16, dead before UV GEMM
        patchb16= (u16*)(ws + R0 + UVSZ);
        p1      = nullptr;
        p2      = nullptr;
        size_t tb = (ws_size - TAIL) & ~(size_t)255;
        w1t  = (u16*)(ws + tb);
        w2t  = (u16*)(ws + tb + 786432);
        gwt  = (u16*)(ws + tb + 1196032);
        uvwt = (u16*)(ws + tb + 1516032);       // 1600*400*2 = 1,280,000
        hw2t = (u16*)(ws + tb + 2796032);
        a_s  = (float*)(ws + tb + 3436032);
        a_d  = (float*)(ws + tb + 3698176);
        deg  = (int*)(ws + tb + 3960320);
    } else {
        enc1    = (u16*)ws;                     // sequenced overlays
        whb     = (u16*)ws;
        p1      = (u16*)ws;
        featb16 = nullptr;
        patchb16= nullptr;
        encb16  = nullptr;
        part    = nullptr;
        p2      = (u16*)(ws + 26214400);
        uv      = (u16*)(ws + 39321600);        // 1024*1600*2 = 3,276,800
        w1t  = (u16*)(ws + 42598400);
        w2t  = (u16*)(ws + 43384832);
        gwt  = (u16*)(ws + 43794432);
        uvwt = (u16*)(ws + 44114432);
        hw2t = (u16*)(ws + 45394432);
        a_s  = (float*)(ws + 46034432);
        a_d  = (float*)(ws + 46296576);
        deg  = (int*)(ws + 46558720);
    }
    int* row_ptr = deg + 1024;
    int* cnt     = row_ptr + 1032;
    int* col_src = cnt + 1024;
    u16* zbuf = (u16*)(col_src + 17408);        // 256 B zero scratch (16B aligned)

    hipMemsetAsync(zbuf, 0, 256, stream);

    // weight transposes (bf16), tiny
    wt_k<<<(HID * IN_DIM + 255) / 256, 256, 0, stream>>>(enc_w1, w1t, IN_DIM, HID);
    wt_k<<<(OUT_ * HID + 255) / 256, 256, 0, stream>>>(enc_w2, w2t, HID, OUT_);
    wt_k<<<(OUT_ * OUT_ + 255) / 256, 256, 0, stream>>>(gat_w, gwt, OUT_, OUT_);
    wtuv_k<<<(UVW_ * OUT_ + 255) / 256, 256, 0, stream>>>(h_w1, uvwt);
    wt_k<<<(OUT_ * PAIR_ + 255) / 256, 256, 0, stream>>>(h_w2, hw2t, PAIR_, OUT_);

    // CSR by dst (batch-independent)
    hipMemsetAsync(deg, 0, 1024 * sizeof(int), stream);
    csr_count_k<<<(ET_ + 255) / 256, 256, 0, stream>>>(edges, deg);
    csr_scan_k<<<1, 1024, 0, stream>>>(deg, row_ptr, cnt);
    csr_fill_k<<<(ET_ + 255) / 256, 256, 0, stream>>>(edges, cnt, col_src);

    if (big) {
        // patch -> bf16 once (numerics identical: staging already cvt'd)
        f2b_k<<<(B_ * N_ * IN_DIM / 8 + 255) / 256, 256, 0, stream>>>(
            patch, patchb16, B_ * N_ * IN_DIM / 8);
        // encoder: enc1 = gelu(patch @ w1 + b1)   [wide 256x256]
        mfma_gemm_k<1, true, true, false, false, 1><<<dim3(2, (B_ * N_) / 256), 512, 0, stream>>>(
            nullptr, patchb16, w1t, enc_b1, enc1, nullptr, B_ * N_, HID, IN_DIM, zbuf,
            nullptr, nullptr, nullptr, nullptr, 0);
        // feat(f32, d_out) + encb16(bf16) = enc1 @ w2 + b2
        mfma_gemm_k<1, false, true, true, false, 1><<<dim3(2, (B_ * N_) / 256), 512, 0, stream>>>(
            nullptr, enc1, w2t, enc_b2, encb16, feat, B_ * N_, OUT_, HID, zbuf,
            nullptr, nullptr, nullptr, nullptr, 0);
        // GAT linear: wh = enc(bf16) @ gat_w
        mfma_gemm_k<1, false, false, false, false, 1><<<dim3(2, (B_ * N_) / 256), 512, 0, stream>>>(
            nullptr, encb16, gwt, nullptr, whb, nullptr, B_ * N_, OUT_, OUT_, zbuf,
            nullptr, nullptr, nullptr, nullptr, 0);
    } else {
        mfma_gemm_k<0, true, true, false, false, 0><<<dim3(HID / 128, (B_ * N_) / 128), 256, 0, stream>>>(
            patch, nullptr, w1t, enc_b1, enc1, nullptr, B_ * N_, HID, IN_DIM, zbuf,
            nullptr, nullptr, nullptr, nullptr, 0);
        mfma_gemm_k<1, false, true, true, false, 0><<<dim3((OUT_ + 127) / 128, (B_ * N_) / 128), 256, 0, stream>>>(
            nullptr, enc1, w2t, enc_b2, nullptr, feat, B_ * N_, OUT_, HID, zbuf,
            nullptr, nullptr, nullptr, nullptr, 0);
        mfma_gemm_k<0, false, false, false, false, 0><<<dim3((OUT_ + 127) / 128, (B_ * N_) / 128), 256, 0, stream>>>(
            feat, nullptr, gwt, nullptr, whb, nullptr, B_ * N_, OUT_, OUT_, zbuf,
            nullptr, nullptr, nullptr, nullptr, 0);
    }

    scores_k<<<(B_ * N_) / 4, 256, 0, stream>>>(whb, att_s, att_d, a_s, a_d);
    gat_k<<<B_ * N_, 256, 0, stream>>>(whb, a_s, a_d, row_ptr, col_src,
                                       gat_b, feat, featb16);

    // predict head:
    //   GEMM1 distributed:  UV = feat @ [h_w1_top | h_w1_bot]  (per-node)
    //   GEMM2 gather-fused: A row = gelu(UV[src]+UV[dst|V]+b1) built in
    //   staging (no p1); head3 fused in epilogue (no p2); ONE dispatch.
    if (big) {
        // UV = featb16 @ uvwt  -> bf16 [32768,1600]
        mfma_gemm_k<1, false, false, false, false, 1><<<dim3((UVW_ + 255) / 256, (B_ * N_) / 256), 512, 0, stream>>>(
            nullptr, featb16, uvwt, nullptr, uv, nullptr, B_ * N_, UVW_, OUT_, zbuf,
            nullptr, nullptr, nullptr, nullptr, 0);
        const int Mr = B_ * E_;                  // 524288 rows, one dispatch
        mfma_gemm_k<2, false, true, false, true, 1><<<dim3(2, Mr / 256), 512, 0, stream>>>(
            h_b1 /*b1 via Af*/, uv /*UV via Ab*/, hw2t, h_b2, nullptr, nullptr,
            Mr, OUT_, PAIR_, zbuf, h_w3, part, src0, dst0, 0);
        red3_k<<<(Mr + 255) / 256, 256, 0, stream>>>(part, h_b3, out, 0, Mr, 2);
    } else {
        for (int b = 0; b < B_; ++b) {
            const float* featb = feat + (size_t)b * N_ * OUT_;
            mfma_gemm_k<0, false, false, false, false, 0><<<dim3((UVW_ + 127) / 128, N_ / 128), 256, 0, stream>>>(
                featb, nullptr, uvwt, nullptr, uv, nullptr, N_, UVW_, OUT_, zbuf,
                nullptr, nullptr, nullptr, nullptr, 0);
            pair_fuse_k<<<(E_ * 100 + 255) / 256, 256, 0, stream>>>(
                uv, h_b1, src0, dst0, p1, -1, E_);
            mfma_gemm_k<1, true, true, false, false, 0><<<dim3((OUT_ + 127) / 128, E_ / 128), 256, 0, stream>>>(
                nullptr, p1, hw2t, h_b2, p2, nullptr, E_, OUT_, PAIR_, zbuf,
                nullptr, nullptr, nullptr, nullptr, 0);
            head3_k<<<(E_ + 15) / 16, 256, 0, stream>>>(p2, h_w3, h_b3, out,
                                                        b * E_, E_);
        }
    }
}

// Round 10
// 1572.887 us; speedup vs baseline: 1.1505x; 1.1505x over previous
//
#include <hip/hip_runtime.h>
#include <hip/hip_bf16.h>

typedef unsigned short u16;   // bf16 bits
typedef __attribute__((ext_vector_type(8))) short bf16x8;   // MFMA A/B frag
typedef __attribute__((ext_vector_type(4))) float f32x4;    // MFMA C/D frag

#define B_   32
#define N_   1024
#define E_   16384
#define ET_  17408            // E_ + N_ self-loops
#define IN_DIM 768
#define HID  512
#define OUT_ 400
#define PAIR_ 800
#define UVW_ 1600             // U(800) ++ V(800) per node
#define FEAT_ELEMS 13107200   // B_*N_*OUT_
#define MAXD 128
#define MRC  32768            // head chunk rows (CB=2), power of 2
#define NPAN 13               // ceil(800/64) K-panels

__device__ __forceinline__ float u2f(u16 u) {
    union { unsigned int i; float f; } v; v.i = ((unsigned int)u) << 16; return v.f;
}
__device__ __forceinline__ u16 f2u(float f) {
    __hip_bfloat16 h = __float2bfloat16(f);   // RNE, HW cvt on gfx950
    return *(u16*)&h;
}
__device__ __forceinline__ unsigned int pack2(float a, float b) {
    return (unsigned int)f2u(a) | ((unsigned int)f2u(b) << 16);
}

__device__ __forceinline__ float gelu_f(float x) {
    const float c = 0.7978845608028654f;          // sqrt(2/pi)
    float u = c * (x + 0.044715f * x * x * x);
    float t = 2.0f / (1.0f + __expf(-2.0f * u)) - 1.0f;   // tanh(u), overflow-safe
    return 0.5f * x * (1.0f + t);
}

// async global->LDS, 16 B per lane; LDS dest is wave-uniform base + lane*16
__device__ __forceinline__ void load_lds16(const void* g, void* l) {
    __builtin_amdgcn_global_load_lds(
        (const __attribute__((address_space(1))) void*)g,
        (__attribute__((address_space(3))) void*)l, 16, 0, 0);
}

// ---------------------------------------------------------------------------
// Weight transpose + bf16 convert: Wt[n][k] = bf16(W[k][n]). Tiny, once/launch.
// ---------------------------------------------------------------------------
__global__ void wt_k(const float* __restrict__ W, u16* __restrict__ Wt,
                     int K, int N)
{
    int i = blockIdx.x * 256 + threadIdx.x;
    if (i >= N * K) return;
    int n = i / K, k = i - n * K;
    Wt[i] = f2u(W[(size_t)k * N + n]);
}

// h_w1 [800][800] -> uvwt [1600][400] bf16 (transposed, halves split)
__global__ void wtuv_k(const float* __restrict__ W, u16* __restrict__ Wt)
{
    int i = blockIdx.x * 256 + threadIdx.x;       // over 1600*400
    if (i >= UVW_ * OUT_) return;
    int n = i / OUT_, k = i - n * OUT_;
    int row = (n >= PAIR_) ? OUT_ + k : k;
    int col = (n >= PAIR_) ? n - PAIR_ : n;
    Wt[i] = f2u(W[(size_t)row * PAIR_ + col]);
}

// f32 -> bf16 bulk convert, 8 elems/lane
__global__ void f2b_k(const float* __restrict__ X, u16* __restrict__ Y, int n8)
{
    int i = blockIdx.x * 256 + threadIdx.x;
    if (i >= n8) return;
    const float4* p = (const float4*)X + (size_t)i * 2;
    float4 a = p[0], b = p[1];
    uint4 o;
    o.x = pack2(a.x, a.y); o.y = pack2(a.z, a.w);
    o.z = pack2(b.x, b.y); o.w = pack2(b.z, b.w);
    ((uint4*)Y)[i] = o;
}

// ---------------------------------------------------------------------------
// MFMA GEMM: C[M,N] = act(A[M,K] @ W[K,N] + bias), f32 accumulate.
// SHAPE 0: 128x128, BK=64, 4 waves (small-mode legacy; ASRC 0/1)
// SHAPE 1: 256x256, BK=64, 8 waves, wave=64x128, LDS 128KB dbuf.
// ASRC: 0 = f32 A (VGPR cvt staging, SHAPE0 only)
//       1 = bf16 A row-major [M][K] (async global_load_lds)
//       3 = bf16 A K-PANEL [K/64][M][64] (async global_load_lds). r4-r7
//           showed head GEMM2 pinned at ~550GB/s A-fetch: K-strided tiling
//           of row-major A reads 128B per 1600B row per window, re-activating
//           every DRAM page 13x. Panel layout makes each window one
//           contiguous slab (and panel pitch 128B == LDS tile pitch, so the
//           verified staging/read math is unchanged except the base addr).
// 2-phase pipeline: stage(next) BEFORE compute; counted vmcnt(8); raw barrier.
// T1 XCD-chunked bijective swizzle (m204) for L2 locality of A panels.
// FUSE_H3: no C store; contract tile with w3 [N][3] after gelu(.+bias):
// shfl over lm, LDS-combine wn-wave pairs, non-atomic part[bnIdx][row][3];
// red3_k sums gx slices + b3 (r3 atomic version was 48MB write-through).
// LDS XOR swizzle phys_chunk=log_chunk^(row&7): global_load_lds contiguity
// AND conflict-free ds_read_b128 (m136). OOB lanes read zbuf.
// ---------------------------------------------------------------------------
template<int ASRC, bool DO_GELU, bool HAS_BIAS, bool OUT_F32, bool FUSE_H3, int SHAPE>
__global__ __launch_bounds__(SHAPE >= 1 ? 512 : 256, 2)
void mfma_gemm_k(const float* __restrict__ Af, const u16* __restrict__ Ab,
                 const u16* __restrict__ Wt, const float* __restrict__ bias,
                 u16* __restrict__ Cb, float* __restrict__ Cf,
                 int M, int N, int K,
                 const u16* __restrict__ zbuf,
                 const float* __restrict__ w3p, float* __restrict__ partp)
{
    static_assert(SHAPE == 0 || ASRC >= 1, "wide shapes need bf16 async staging");
    constexpr int BM  = (SHAPE == 1) ? 256 : 128;
    constexpr int BN  = (SHAPE == 1) ? 256 : 128;
    constexpr int UN  = (SHAPE == 1) ? 8 : 4;      // 16-col frags per wave
    constexpr int CW  = 2;                         // col-waves per row-group

    __shared__ __align__(16) u16 As[2][BM * 64];
    __shared__ __align__(16) u16 Bs[2][BN * 64];
    const int tid  = threadIdx.x;
    // --- T1 bijective XCD swizzle ---
    const int gx   = gridDim.x;
    const int nwg  = gx * gridDim.y;
    const int orig = blockIdx.y * gx + blockIdx.x;
    const int qc   = nwg >> 3, rc = nwg & 7;
    const int xcd  = orig & 7, lid = orig >> 3;
    const int wg   = ((xcd < rc) ? xcd * (qc + 1) : rc * (qc + 1) + (xcd - rc) * qc) + lid;
    const int bnIdx= wg % gx;
    const int bm   = (wg / gx) * BM;
    const int bn   = bnIdx * BN;
    const int wave = tid >> 6;
    const int lane = tid & 63;
    const int wm   = (wave >> 1) * 64;
    const int wn   = (SHAPE == 1) ? (wave & 1) * 128 : (wave & 1) * 64;
    const int lm   = lane & 15;
    const int lq   = lane >> 4;
    const int lb   = lm & 7;
    // staging lane geometry: instr c4 covers rows wave*32+c4*8 .. +7
    const int l8 = lane >> 3;            // row within 8-row group
    const int cl = (lane & 7) ^ l8;      // pre-swizzled 8-elem chunk (0..7)

    // per-c4 row metadata (wave*32 row groups cover BM rows)
    size_t arow[4]; size_t brow[4]; bool bok[4];
    #pragma unroll
    for (int c4 = 0; c4 < 4; ++c4) {
        int rt = wave * 32 + c4 * 8 + l8;          // tile row
        if (ASRC == 1) arow[c4] = (size_t)(bm + rt) * K;
        if (ASRC == 3) arow[c4] = (size_t)(bm + rt) * 64;   // offset in panel
        int n = bn + rt;
        bok[c4] = (n < N);
        brow[c4] = (size_t)(n < N ? n : 0) * K;
    }
    // VGPR-staging geometry (ASRC 0, SHAPE 0 only)
    const int vrow = tid >> 1, vhalf = tid & 1;

    f32x4 acc[4][UN] = {};
    const int NT = (K + 63) >> 6;

    if (ASRC >= 1) {
        auto stage = [&](int buf, int k0) {
            int kk = k0 + cl * 8;
            if (ASRC == 3) {
                const u16* pan = Ab + (size_t)(k0 >> 6) * M * 64;
                #pragma unroll
                for (int c4 = 0; c4 < 4; ++c4) {
                    const u16* ga = (kk < K) ? pan + arow[c4] + cl * 8 : zbuf;
                    load_lds16(ga, (char*)As[buf] + (wave * 32 + c4 * 8) * 128);
                }
            } else {
                #pragma unroll
                for (int c4 = 0; c4 < 4; ++c4) {
                    const u16* ga = (kk < K) ? Ab + arow[c4] + kk : zbuf;
                    load_lds16(ga, (char*)As[buf] + (wave * 32 + c4 * 8) * 128);
                }
            }
            #pragma unroll
            for (int c4 = 0; c4 < 4; ++c4) {
                const u16* gb = (bok[c4] && kk < K) ? Wt + brow[c4] + kk : zbuf;
                load_lds16(gb, (char*)Bs[buf] + (wave * 32 + c4 * 8) * 128);
            }
        };
        stage(0, 0);
        int cur = 0;
        for (int it = 0; it < NT; ++it) {
            const bool last = (it == NT - 1);
            if (!last) stage(cur ^ 1, (it + 1) * 64);
            if (!last) asm volatile("s_waitcnt vmcnt(8)" ::: "memory");
            else       asm volatile("s_waitcnt vmcnt(0)" ::: "memory");
            __builtin_amdgcn_s_barrier();
            const char* Abase = (const char*)As[cur];
            const char* Bbase = (const char*)Bs[cur];
            #pragma unroll
            for (int kh = 0; kh < 2; ++kh) {
                bf16x8 af[4], bfr[UN];
                #pragma unroll
                for (int t = 0; t < 4; ++t)
                    af[t] = *(const bf16x8*)(Abase +
                            (wm + t * 16 + lm) * 128 + (((kh * 4 + lq) ^ lb) * 16));
                #pragma unroll
                for (int u = 0; u < UN; ++u)
                    bfr[u] = *(const bf16x8*)(Bbase +
                            (wn + u * 16 + lm) * 128 + (((kh * 4 + lq) ^ lb) * 16));
                #pragma unroll
                for (int t = 0; t < 4; ++t)
                    #pragma unroll
                    for (int u = 0; u < UN; ++u)
                        acc[t][u] = __builtin_amdgcn_mfma_f32_16x16x32_bf16(
                            af[t], bfr[u], acc[t][u], 0, 0, 0);
            }
            asm volatile("" ::: "memory");
            __builtin_amdgcn_s_barrier();
            cur ^= 1;
        }
    } else {
        for (int k0 = 0; k0 < K; k0 += 64) {
            // ---- stage A (VGPR cvt, SHAPE0 only)
            #pragma unroll
            for (int c = 0; c < 4; ++c) {
                int c_log = vhalf * 4 + c;
                int kk = k0 + c_log * 8;
                uint4 wv = make_uint4(0, 0, 0, 0);
                if (kk < K) {
                    const float* p = Af + (size_t)(bm + vrow) * K + kk;
                    float4 v0 = *(const float4*)p;
                    float4 v1 = *(const float4*)(p + 4);
                    wv.x = pack2(v0.x, v0.y); wv.y = pack2(v0.z, v0.w);
                    wv.z = pack2(v1.x, v1.y); wv.w = pack2(v1.z, v1.w);
                }
                int pc = c_log ^ (vrow & 7);
                *(uint4*)((char*)As[0] + vrow * 128 + pc * 16) = wv;
            }
            // ---- stage B (async)
            {
                int kk = k0 + cl * 8;
                #pragma unroll
                for (int c4 = 0; c4 < 4; ++c4) {
                    const u16* gb = (bok[c4] && kk < K) ? Wt + brow[c4] + kk : zbuf;
                    load_lds16(gb, (char*)Bs[0] + (wave * 32 + c4 * 8) * 128);
                }
            }
            __syncthreads();
            #pragma unroll
            for (int kh = 0; kh < 2; ++kh) {
                bf16x8 af[4], bfr[UN];
                #pragma unroll
                for (int t = 0; t < 4; ++t)
                    af[t] = *(const bf16x8*)((const char*)As[0] +
                            (wm + t * 16 + lm) * 128 + (((kh * 4 + lq) ^ lb) * 16));
                #pragma unroll
                for (int u = 0; u < UN; ++u)
                    bfr[u] = *(const bf16x8*)((const char*)Bs[0] +
                            (wn + u * 16 + lm) * 128 + (((kh * 4 + lq) ^ lb) * 16));
                #pragma unroll
                for (int t = 0; t < 4; ++t)
                    #pragma unroll
                    for (int u = 0; u < UN; ++u)
                        acc[t][u] = __builtin_amdgcn_mfma_f32_16x16x32_bf16(
                            af[t], bfr[u], acc[t][u], 0, 0, 0);
            }
            __syncthreads();
        }
    }

    // ---- fused head3 epilogue: part[bnIdx][row] = gelu(p2_tile) @ w3
    if (FUSE_H3) {
        float w3c[UN][3]; float bvv[UN];
        #pragma unroll
        for (int u = 0; u < UN; ++u) {
            int col = bn + wn + u * 16 + lm;
            bool ok = (col < N);
            bvv[u]    = ok ? bias[col] : 0.f;
            w3c[u][0] = ok ? w3p[col * 3 + 0] : 0.f;
            w3c[u][1] = ok ? w3p[col * 3 + 1] : 0.f;
            w3c[u][2] = ok ? w3p[col * 3 + 2] : 0.f;
        }
        float* red = (float*)As;         // [waves][64 rows][3] floats, As dead
        #pragma unroll
        for (int t = 0; t < 4; ++t) {
            #pragma unroll
            for (int r = 0; r < 4; ++r) {
                float s0 = 0.f, s1 = 0.f, s2 = 0.f;
                #pragma unroll
                for (int u = 0; u < UN; ++u) {
                    float v = gelu_f(acc[t][u][r] + bvv[u]);
                    s0 += v * w3c[u][0];
                    s1 += v * w3c[u][1];
                    s2 += v * w3c[u][2];
                }
                #pragma unroll
                for (int off = 8; off; off >>= 1) {
                    s0 += __shfl_xor(s0, off);
                    s1 += __shfl_xor(s1, off);
                    s2 += __shfl_xor(s2, off);
                }
                if (lm == 0) {
                    int lr = t * 16 + lq * 4 + r;            // 0..63 within wave
                    float* d = red + (wave * 64 + lr) * 3;
                    d[0] = s0; d[1] = s1; d[2] = s2;
                }
            }
        }
        __syncthreads();
        if ((wave & (CW - 1)) == 0) {     // lead wave of each row-group pair
            int lr = lane;
            int rowg = bm + wm + lr;
            float s0 = 0.f, s1 = 0.f, s2 = 0.f;
            #pragma unroll
            for (int w = 0; w < CW; ++w) {
                float* a = red + ((wave + w) * 64 + lr) * 3;
                s0 += a[0]; s1 += a[1]; s2 += a[2];
            }
            float* d = partp + ((size_t)bnIdx * M + rowg) * 3;
            d[0] = s0; d[1] = s1; d[2] = s2;
        }
        return;
    }

    // ---- epilogue: C col = lane&15, row = quad*4 + reg (verified m89/m91)
    #pragma unroll
    for (int u = 0; u < UN; ++u) {
        int col = bn + wn + u * 16 + lm;
        if (col >= N) continue;
        float bv = HAS_BIAS ? bias[col] : 0.f;
        #pragma unroll
        for (int t = 0; t < 4; ++t) {
            #pragma unroll
            for (int r = 0; r < 4; ++r) {
                int rowg = bm + wm + t * 16 + lq * 4 + r;
                float v = acc[t][u][r] + bv;
                if (DO_GELU) v = gelu_f(v);
                if (OUT_F32) {
                    Cf[(size_t)rowg * N + col] = v;
                    if (Cb) Cb[(size_t)rowg * N + col] = f2u(v);  // dual write
                } else {
                    Cb[(size_t)rowg * N + col] = f2u(v);
                }
            }
        }
    }
}

// ---------------------------------------------------------------------------
// Partial reduce: pred[row_base+r,:] = b3 + sum_{s<ns} part[s][r][:]
// ---------------------------------------------------------------------------
__global__ __launch_bounds__(256)
void red3_k(const float* __restrict__ part, const float* __restrict__ b3,
            float* __restrict__ out, int row_base, int Mr, int ns)
{
    int r = blockIdx.x * 256 + threadIdx.x;
    if (r >= Mr) return;
    float s0 = b3[0], s1 = b3[1], s2 = b3[2];
    for (int s = 0; s < ns; ++s) {
        const float* p = part + ((size_t)s * Mr + r) * 3;
        s0 += p[0]; s1 += p[1]; s2 += p[2];
    }
    float* d = out + (size_t)FEAT_ELEMS + (size_t)(row_base + r) * 3;
    d[0] = s0; d[1] = s1; d[2] = s2;
}

// ---------------------------------------------------------------------------
// Pair fuse, K-PANEL output: p1k[p][MRC][64] = gelu(U[src]+V[dst]+b1) slices.
// idx = (p*MRC + r)*8 + s  (all shifts: MRC=2^15) -> consecutive threads
// write consecutive 16B chunks of the panel slab (fully streaming) and read
// 128B-coalesced UV row slices. p=12,s>=4 (cols>=800) skipped (never read:
// GEMM2 staging guards kk<K via zbuf).
// ---------------------------------------------------------------------------
__global__ __launch_bounds__(256)
void pair_fuse_kp(const u16* __restrict__ UV, const float* __restrict__ b1,
                  const int* __restrict__ src0, const int* __restrict__ dst0,
                  u16* __restrict__ p1k, int b0)
{
    unsigned idx = blockIdx.x * 256u + threadIdx.x;
    unsigned s = idx & 7u;
    unsigned r = (idx >> 3) & (MRC - 1);
    unsigned p = idx >> 18;                 // 3 + 15
    if (p >= NPAN) return;
    int k0 = (int)(p * 64 + s * 8);
    if (k0 >= PAIR_) return;
    int e = (int)(r & (E_ - 1));
    int b = b0 + (int)(r >> 14);
    int gs = (b << 10) + src0[e];
    int gd = (b << 10) + dst0[e];
    uint4 qu = *(const uint4*)(UV + (size_t)gs * UVW_ + k0);
    uint4 qv = *(const uint4*)(UV + (size_t)gd * UVW_ + PAIR_ + k0);
    float4 bva = *(const float4*)(b1 + k0);
    float4 bvb = *(const float4*)(b1 + k0 + 4);
    float bb[8] = {bva.x, bva.y, bva.z, bva.w, bvb.x, bvb.y, bvb.z, bvb.w};
    unsigned int uu[4] = {qu.x, qu.y, qu.z, qu.w};
    unsigned int vv[4] = {qv.x, qv.y, qv.z, qv.w};
    uint4 o; unsigned int* op = (unsigned int*)&o;
    #pragma unroll
    for (int q = 0; q < 4; ++q) {
        float a0 = u2f((u16)(uu[q] & 0xffff)) + u2f((u16)(vv[q] & 0xffff)) + bb[2*q];
        float a1 = u2f((u16)(uu[q] >> 16))    + u2f((u16)(vv[q] >> 16))    + bb[2*q+1];
        op[q] = pack2(gelu_f(a0), gelu_f(a1));
    }
    *(uint4*)(p1k + ((size_t)p * MRC + r) * 64 + s * 8) = o;
}

// ---------------------------------------------------------------------------
// Pair fuse (small mode only): p1[r,:] = gelu(U[src] + V[dst] + b1).
// ---------------------------------------------------------------------------
__global__ __launch_bounds__(256)
void pair_fuse_k(const u16* __restrict__ UV, const float* __restrict__ b1,
                 const int* __restrict__ src0, const int* __restrict__ dst0,
                 u16* __restrict__ p1, int b0, int nrows)
{
    unsigned idx = blockIdx.x * 256u + threadIdx.x;
    unsigned total = (unsigned)nrows * 100u;
    if (idx >= total) return;
    unsigned r  = (unsigned)(((unsigned long long)idx * 1374389535ull) >> 37); // /100
    unsigned c8 = idx - r * 100u;
    int e = r & (E_ - 1);
    int gs, gd;
    if (b0 >= 0) {
        int b = b0 + (int)(r >> 14);
        gs = (b << 10) + src0[e];
        gd = (b << 10) + dst0[e];
    } else {
        gs = src0[e]; gd = dst0[e];
    }
    uint4 qu = *(const uint4*)(UV + (size_t)gs * UVW_ + c8 * 8);
    uint4 qv = *(const uint4*)(UV + (size_t)gd * UVW_ + PAIR_ + c8 * 8);
    float4 bva = *(const float4*)(b1 + c8 * 8);
    float4 bvb = *(const float4*)(b1 + c8 * 8 + 4);
    float bb[8] = {bva.x, bva.y, bva.z, bva.w, bvb.x, bvb.y, bvb.z, bvb.w};
    unsigned int uu[4] = {qu.x, qu.y, qu.z, qu.w};
    unsigned int vv[4] = {qv.x, qv.y, qv.z, qv.w};
    uint4 o; unsigned int* op = (unsigned int*)&o;
    #pragma unroll
    for (int q = 0; q < 4; ++q) {
        float a0 = u2f((u16)(uu[q] & 0xffff)) + u2f((u16)(vv[q] & 0xffff)) + bb[2*q];
        float a1 = u2f((u16)(uu[q] >> 16))    + u2f((u16)(vv[q] >> 16))    + bb[2*q+1];
        op[q] = pack2(gelu_f(a0), gelu_f(a1));
    }
    *(uint4*)(p1 + (size_t)r * PAIR_ + c8 * 8) = o;
}

// ---------------------------------------------------------------------------
// Attention scores
// ---------------------------------------------------------------------------
__global__ __launch_bounds__(256)
void scores_k(const u16* __restrict__ wh, const float* __restrict__ att_s,
              const float* __restrict__ att_d, float* __restrict__ a_s,
              float* __restrict__ a_d)
{
    int n = blockIdx.x * 4 + (threadIdx.x >> 6);
    int lane = threadIdx.x & 63;
    const u16* row = wh + (size_t)n * OUT_;
    float as0 = 0, as1 = 0, ad0 = 0, ad1 = 0;
    for (int f = lane; f < OUT_; f += 64) {
        float v = u2f(row[f]);
        float s = att_s[f];
        float d = att_d[f];
        if (f < 200) { as0 += v * s; ad0 += v * d; }
        else         { as1 += v * s; ad1 += v * d; }
    }
    for (int off = 32; off; off >>= 1) {
        as0 += __shfl_xor(as0, off); as1 += __shfl_xor(as1, off);
        ad0 += __shfl_xor(ad0, off); ad1 += __shfl_xor(ad1, off);
    }
    if (lane == 0) {
        a_s[(size_t)n * 2 + 0] = as0; a_s[(size_t)n * 2 + 1] = as1;
        a_d[(size_t)n * 2 + 0] = ad0; a_d[(size_t)n * 2 + 1] = ad1;
    }
}

// ---------------------------------------------------------------------------
// CSR build (edges shared across batches; incl. self-loops)
// ---------------------------------------------------------------------------
__global__ void csr_count_k(const int* __restrict__ edges, int* __restrict__ deg)
{
    int et = blockIdx.x * blockDim.x + threadIdx.x;
    if (et >= ET_) return;
    int dst = (et < E_) ? edges[E_ + et] : (et - E_);
    atomicAdd(&deg[dst], 1);
}

__global__ __launch_bounds__(1024)
void csr_scan_k(const int* __restrict__ deg, int* __restrict__ row_ptr,
                int* __restrict__ cnt)
{
    __shared__ int s[1024];
    int t = threadIdx.x;
    int d = deg[t];
    s[t] = d;
    __syncthreads();
    for (int off = 1; off < 1024; off <<= 1) {
        int v = (t >= off) ? s[t - off] : 0;
        __syncthreads();
        s[t] += v;
        __syncthreads();
    }
    row_ptr[t] = s[t] - d;   // exclusive
    cnt[t] = s[t] - d;
    if (t == 1023) row_ptr[1024] = s[t];
}

__global__ void csr_fill_k(const int* __restrict__ edges, int* __restrict__ cnt,
                           int* __restrict__ col_src)
{
    int et = blockIdx.x * blockDim.x + threadIdx.x;
    if (et >= ET_) return;
    int src, dst;
    if (et < E_) { src = edges[et]; dst = edges[E_ + et]; }
    else         { src = et - E_;  dst = src; }
    int pos = atomicAdd(&cnt[dst], 1);
    col_src[pos] = src;
}

// ---------------------------------------------------------------------------
// Fused GAT softmax + aggregation + residual, in place on f32 feat (d_out).
// ---------------------------------------------------------------------------
__global__ __launch_bounds__(256)
void gat_k(const u16* __restrict__ wh,
           const float* __restrict__ a_s, const float* __restrict__ a_d,
           const int* __restrict__ row_ptr, const int* __restrict__ col_src,
           const float* __restrict__ gat_b, float* __restrict__ feat,
           u16* __restrict__ featb16)
{
    int gn = blockIdx.x;                  // b*1024 + n
    int b = gn >> 10, n = gn & 1023;
    int tid = threadIdx.x;
    __shared__ float s_ee[2][MAXD];
    __shared__ int   s_src[MAXD];
    __shared__ float s_misc[6];           // m0,m1,invz0,invz1,ad0,ad1
    __shared__ float s_part[4][50][9];    // +1 pad col: spread banks
    int start = row_ptr[n];
    int deg = row_ptr[n + 1] - start;

    if (tid < 64) {
        int lane = tid;
        float ad0 = a_d[(size_t)gn * 2 + 0];
        float ad1 = a_d[(size_t)gn * 2 + 1];
        float m0 = -1e30f, m1 = -1e30f;
        for (int j = lane; j < deg; j += 64) {
            int gs = (b << 10) + col_src[start + j];
            float e0 = a_s[(size_t)gs * 2 + 0] + ad0; e0 = (e0 > 0.f) ? e0 : 0.2f * e0;
            float e1 = a_s[(size_t)gs * 2 + 1] + ad1; e1 = (e1 > 0.f) ? e1 : 0.2f * e1;
            if (j < MAXD) { s_ee[0][j] = e0; s_ee[1][j] = e1; s_src[j] = gs; }
            m0 = fmaxf(m0, e0); m1 = fmaxf(m1, e1);
        }
        for (int off = 32; off; off >>= 1) {
            m0 = fmaxf(m0, __shfl_xor(m0, off));
            m1 = fmaxf(m1, __shfl_xor(m1, off));
        }
        float z0 = 0.f, z1 = 0.f;
        for (int j = lane; j < deg; j += 64) {
            float e0, e1;
            if (j < MAXD) { e0 = s_ee[0][j]; e1 = s_ee[1][j]; }
            else {
                int gs = (b << 10) + col_src[start + j];
                e0 = a_s[(size_t)gs * 2 + 0] + ad0; e0 = (e0 > 0.f) ? e0 : 0.2f * e0;
                e1 = a_s[(size_t)gs * 2 + 1] + ad1; e1 = (e1 > 0.f) ? e1 : 0.2f * e1;
            }
            float t0 = __expf(e0 - m0), t1 = __expf(e1 - m1);
            if (j < MAXD) { s_ee[0][j] = t0; s_ee[1][j] = t1; }
            z0 += t0; z1 += t1;
        }
        for (int off = 32; off; off >>= 1) {
            z0 += __shfl_xor(z0, off);
            z1 += __shfl_xor(z1, off);
        }
        if (lane == 0) {
            s_misc[0] = m0; s_misc[1] = m1;
            s_misc[2] = (z0 > 0.f) ? 1.f / z0 : 0.f;
            s_misc[3] = (z1 > 0.f) ? 1.f / z1 : 0.f;
            s_misc[4] = ad0; s_misc[5] = ad1;
        }
    }
    __syncthreads();

    int wv = tid >> 6, ln = tid & 63;
    if (ln < 50) {
        int h = (ln >= 25);
        float m = s_misc[h], ad = s_misc[4 + h];
        float acc[8] = {};
        for (int j = wv; j < deg; j += 4) {
            float w; int gs;
            if (j < MAXD) { w = s_ee[h][j]; gs = s_src[j]; }
            else {
                gs = (b << 10) + col_src[start + j];
                float e = a_s[(size_t)gs * 2 + h] + ad;
                e = (e > 0.f) ? e : 0.2f * e;
                w = __expf(e - m);
            }
            uint4 q = *(const uint4*)(wh + (size_t)gs * OUT_ + ln * 8);
            acc[0] += w * u2f((u16)(q.x & 0xffff));
            acc[1] += w * u2f((u16)(q.x >> 16));
            acc[2] += w * u2f((u16)(q.y & 0xffff));
            acc[3] += w * u2f((u16)(q.y >> 16));
            acc[4] += w * u2f((u16)(q.z & 0xffff));
            acc[5] += w * u2f((u16)(q.z >> 16));
            acc[6] += w * u2f((u16)(q.w & 0xffff));
            acc[7] += w * u2f((u16)(q.w >> 16));
        }
        #pragma unroll
        for (int k = 0; k < 8; ++k) s_part[wv][ln][k] = acc[k];
    }
    __syncthreads();
    if (tid < 50) {
        int h = (tid >= 25);
        float iz = s_misc[2 + h];
        size_t base = (size_t)gn * OUT_ + tid * 8;
        float4 f0 = *(const float4*)(feat + base);
        float4 f1 = *(const float4*)(feat + base + 4);
        float fv[8] = { f0.x, f0.y, f0.z, f0.w, f1.x, f1.y, f1.z, f1.w };
        float o[8];
        #pragma unroll
        for (int k = 0; k < 8; ++k) {
            float s = s_part[0][tid][k] + s_part[1][tid][k] +
                      s_part[2][tid][k] + s_part[3][tid][k];
            o[k] = fv[k] + s * iz + gat_b[tid * 8 + k];
        }
        *(float4*)(feat + base)     = make_float4(o[0], o[1], o[2], o[3]);
        *(float4*)(feat + base + 4) = make_float4(o[4], o[5], o[6], o[7]);
        if (featb16) {
            uint4 bq;
            bq.x = pack2(o[0], o[1]); bq.y = pack2(o[2], o[3]);
            bq.z = pack2(o[4], o[5]); bq.w = pack2(o[6], o[7]);
            *(uint4*)(featb16 + base) = bq;
        }
    }
}

// ---------------------------------------------------------------------------
// Final tiny GEMM (small-mode only): pred[e,:] = p2[e,:] @ w3[400,3] + b3.
// ---------------------------------------------------------------------------
__global__ __launch_bounds__(256)
void head3_k(const u16* __restrict__ p2, const float* __restrict__ w3,
             const float* __restrict__ b3, float* __restrict__ out,
             int row_base, int nrows)
{
    int wv = threadIdx.x >> 6, lane = threadIdx.x & 63;
    float w3r[24];
    if (lane < 50) {
        #pragma unroll
        for (int q = 0; q < 6; ++q) {
            float4 v = *(const float4*)(w3 + lane * 24 + q * 4);
            w3r[q * 4 + 0] = v.x; w3r[q * 4 + 1] = v.y;
            w3r[q * 4 + 2] = v.z; w3r[q * 4 + 3] = v.w;
        }
    }
    int e0 = blockIdx.x * 16 + wv * 4;
    for (int ei = 0; ei < 4; ++ei) {
        int e = e0 + ei;
        if (e >= nrows) break;
        float s0 = 0, s1 = 0, s2 = 0;
        if (lane < 50) {
            uint4 q = *(const uint4*)(p2 + (size_t)e * OUT_ + lane * 8);
            float f[8];
            f[0] = u2f((u16)(q.x & 0xffff)); f[1] = u2f((u16)(q.x >> 16));
            f[2] = u2f((u16)(q.y & 0xffff)); f[3] = u2f((u16)(q.y >> 16));
            f[4] = u2f((u16)(q.z & 0xffff)); f[5] = u2f((u16)(q.z >> 16));
            f[6] = u2f((u16)(q.w & 0xffff)); f[7] = u2f((u16)(q.w >> 16));
            #pragma unroll
            for (int k = 0; k < 8; ++k) {
                s0 += f[k] * w3r[k * 3 + 0];
                s1 += f[k] * w3r[k * 3 + 1];
                s2 += f[k] * w3r[k * 3 + 2];
            }
        }
        for (int off = 32; off; off >>= 1) {
            s0 += __shfl_xor(s0, off);
            s1 += __shfl_xor(s1, off);
            s2 += __shfl_xor(s2, off);
        }
        if (lane == 0) {
            size_t o = (size_t)FEAT_ELEMS + (size_t)(row_base + e) * 3;
            out[o + 0] = s0 + b3[0];
            out[o + 1] = s1 + b3[1];
            out[o + 2] = s2 + b3[2];
        }
    }
}

extern "C" void kernel_launch(void* const* d_in, const int* in_sizes, int n_in,
                              void* d_out, int out_size, void* d_ws, size_t ws_size,
                              hipStream_t stream)
{
    const float* patch  = (const float*)d_in[0];
    const int*   edges  = (const int*)d_in[1];
    const float* enc_w1 = (const float*)d_in[2];
    const float* enc_b1 = (const float*)d_in[3];
    const float* enc_w2 = (const float*)d_in[4];
    const float* enc_b2 = (const float*)d_in[5];
    const float* gat_w  = (const float*)d_in[6];
    const float* att_s  = (const float*)d_in[7];
    const float* att_d  = (const float*)d_in[8];
    const float* gat_b  = (const float*)d_in[9];
    const float* h_w1   = (const float*)d_in[10];
    const float* h_b1   = (const float*)d_in[11];
    const float* h_w2   = (const float*)d_in[12];
    const float* h_b2   = (const float*)d_in[13];
    const float* h_w3   = (const float*)d_in[14];
    const float* h_b3   = (const float*)d_in[15];
    float* out  = (float*)d_out;
    float* feat = out;                          // f32 [32768,400] in d_out
    char*  ws   = (char*)d_ws;

    const int* src0 = edges;
    const int* dst0 = edges + E_;

    // --- mode select from ws_size (deterministic; graph-capture safe) ------
    // big-mode layout:
    //   [0,R0)            enc1 bf16; featb16 overlays (dead enc1);
    //                     head-phase: part f32 [2][MRC][3] (786KB)
    //   [R0, R0+26.2MB)   whb bf16 (dead after gat_k)
    //   [R0+26.2,+52.4MB) encb16 bf16 (consumed by GAT linear)
    //   [R0, R0+UVSZ)     UV bf16 [32768,1600] (overlays whb+encb16, after gat)
    //   [R0+UVSZ, +P1K)   p1k K-panel [13][MRC][64] bf16 (54.5MB);
    //                     patchb16 (50.3MB) overlays (dead before head)
    //   [ws_size-TAIL,..) weights + scores + CSR + zbuf
    const size_t R0 = 33554432ull, TAIL = 4194304ull;
    const size_t UVSZ = 104857600ull;            // 32768*1600*2
    const size_t P1K  = (size_t)NPAN * MRC * 64 * 2;  // 54,525,952
    const bool big = (ws_size >= R0 + UVSZ + TAIL + P1K);

    u16 *enc1, *whb, *p1, *p2, *featb16, *uv, *w1t, *w2t, *gwt, *uvwt, *hw2t;
    u16 *patchb16, *encb16, *p1k;
    float *a_s, *a_d, *part; int *deg;
    if (big) {
        enc1    = (u16*)ws;
        featb16 = (u16*)ws;                     // overlays enc1 (dead)
        part    = (float*)ws;                   // head-phase reuse (featb16 dead)
        whb     = (u16*)(ws + R0);
        uv      = (u16*)(ws + R0);              // overlays whb (dead after gat)
        encb16  = (u16*)(ws + R0 + 26214400ull);// enc bf16, dead before UV GEMM
        p1k     = (u16*)(ws + R0 + UVSZ);
        patchb16= (u16*)(ws + R0 + UVSZ);       // overlays p1k (dead before head)
        p1      = nullptr;
        p2      = nullptr;
        size_t tb = (ws_size - TAIL) & ~(size_t)255;
        w1t  = (u16*)(ws + tb);
        w2t  = (u16*)(ws + tb + 786432);
        gwt  = (u16*)(ws + tb + 1196032);
        uvwt = (u16*)(ws + tb + 1516032);       // 1600*400*2 = 1,280,000
        hw2t = (u16*)(ws + tb + 2796032);
        a_s  = (float*)(ws + tb + 3436032);
        a_d  = (float*)(ws + tb + 3698176);
        deg  = (int*)(ws + tb + 3960320);
    } else {
        enc1    = (u16*)ws;                     // sequenced overlays
        whb     = (u16*)ws;
        p1      = (u16*)ws;
        featb16 = nullptr;
        patchb16= nullptr;
        encb16  = nullptr;
        part    = nullptr;
        p1k     = nullptr;
        p2      = (u16*)(ws + 26214400);
        uv      = (u16*)(ws + 39321600);        // 1024*1600*2 = 3,276,800
        w1t  = (u16*)(ws + 42598400);
        w2t  = (u16*)(ws + 43384832);
        gwt  = (u16*)(ws + 43794432);
        uvwt = (u16*)(ws + 44114432);
        hw2t = (u16*)(ws + 45394432);
        a_s  = (float*)(ws + 46034432);
        a_d  = (float*)(ws + 46296576);
        deg  = (int*)(ws + 46558720);
    }
    int* row_ptr = deg + 1024;
    int* cnt     = row_ptr + 1032;
    int* col_src = cnt + 1024;
    u16* zbuf = (u16*)(col_src + 17408);        // 256 B zero scratch (16B aligned)

    hipMemsetAsync(zbuf, 0, 256, stream);

    // weight transposes (bf16), tiny
    wt_k<<<(HID * IN_DIM + 255) / 256, 256, 0, stream>>>(enc_w1, w1t, IN_DIM, HID);
    wt_k<<<(OUT_ * HID + 255) / 256, 256, 0, stream>>>(enc_w2, w2t, HID, OUT_);
    wt_k<<<(OUT_ * OUT_ + 255) / 256, 256, 0, stream>>>(gat_w, gwt, OUT_, OUT_);
    wtuv_k<<<(UVW_ * OUT_ + 255) / 256, 256, 0, stream>>>(h_w1, uvwt);
    wt_k<<<(OUT_ * PAIR_ + 255) / 256, 256, 0, stream>>>(h_w2, hw2t, PAIR_, OUT_);

    // CSR by dst (batch-independent)
    hipMemsetAsync(deg, 0, 1024 * sizeof(int), stream);
    csr_count_k<<<(ET_ + 255) / 256, 256, 0, stream>>>(edges, deg);
    csr_scan_k<<<1, 1024, 0, stream>>>(deg, row_ptr, cnt);
    csr_fill_k<<<(ET_ + 255) / 256, 256, 0, stream>>>(edges, cnt, col_src);

    if (big) {
        // patch -> bf16 once (numerics identical: staging already cvt'd)
        f2b_k<<<(B_ * N_ * IN_DIM / 8 + 255) / 256, 256, 0, stream>>>(
            patch, patchb16, B_ * N_ * IN_DIM / 8);
        // encoder: enc1 = gelu(patch @ w1 + b1)   [wide 256x256]
        mfma_gemm_k<1, true, true, false, false, 1><<<dim3(2, (B_ * N_) / 256), 512, 0, stream>>>(
            nullptr, patchb16, w1t, enc_b1, enc1, nullptr, B_ * N_, HID, IN_DIM, zbuf,
            nullptr, nullptr);
        // feat(f32, d_out) + encb16(bf16) = enc1 @ w2 + b2
        mfma_gemm_k<1, false, true, true, false, 1><<<dim3(2, (B_ * N_) / 256), 512, 0, stream>>>(
            nullptr, enc1, w2t, enc_b2, encb16, feat, B_ * N_, OUT_, HID, zbuf,
            nullptr, nullptr);
        // GAT linear: wh = enc(bf16) @ gat_w
        mfma_gemm_k<1, false, false, false, false, 1><<<dim3(2, (B_ * N_) / 256), 512, 0, stream>>>(
            nullptr, encb16, gwt, nullptr, whb, nullptr, B_ * N_, OUT_, OUT_, zbuf,
            nullptr, nullptr);
    } else {
        mfma_gemm_k<0, true, true, false, false, 0><<<dim3(HID / 128, (B_ * N_) / 128), 256, 0, stream>>>(
            patch, nullptr, w1t, enc_b1, enc1, nullptr, B_ * N_, HID, IN_DIM, zbuf,
            nullptr, nullptr);
        mfma_gemm_k<1, false, true, true, false, 0><<<dim3((OUT_ + 127) / 128, (B_ * N_) / 128), 256, 0, stream>>>(
            nullptr, enc1, w2t, enc_b2, nullptr, feat, B_ * N_, OUT_, HID, zbuf,
            nullptr, nullptr);
        mfma_gemm_k<0, false, false, false, false, 0><<<dim3((OUT_ + 127) / 128, (B_ * N_) / 128), 256, 0, stream>>>(
            feat, nullptr, gwt, nullptr, whb, nullptr, B_ * N_, OUT_, OUT_, zbuf,
            nullptr, nullptr);
    }

    scores_k<<<(B_ * N_) / 4, 256, 0, stream>>>(whb, att_s, att_d, a_s, a_d);
    gat_k<<<B_ * N_, 256, 0, stream>>>(whb, a_s, a_d, row_ptr, col_src,
                                       gat_b, feat, featb16);

    // predict head — GEMM1 distributed (UV); pair_fuse writes K-panel p1k;
    // GEMM2 (ASRC=3 panel-streaming A) fused with head3; red3 sums 2 slices.
    if (big) {
        // UV = featb16 @ uvwt  -> bf16 [32768,1600]
        mfma_gemm_k<1, false, false, false, false, 1><<<dim3((UVW_ + 255) / 256, (B_ * N_) / 256), 512, 0, stream>>>(
            nullptr, featb16, uvwt, nullptr, uv, nullptr, B_ * N_, UVW_, OUT_, zbuf,
            nullptr, nullptr);
        const int PF_BLK = (NPAN * MRC * 8) / 256;   // 13312 blocks
        for (int b0 = 0; b0 < B_; b0 += 2) {
            pair_fuse_kp<<<PF_BLK, 256, 0, stream>>>(uv, h_b1, src0, dst0, p1k, b0);
            mfma_gemm_k<3, false, true, false, true, 1><<<dim3(2, MRC / 256), 512, 0, stream>>>(
                nullptr, p1k, hw2t, h_b2, nullptr, nullptr, MRC, OUT_, PAIR_, zbuf,
                h_w3, part);
            red3_k<<<(MRC + 255) / 256, 256, 0, stream>>>(part, h_b3, out,
                                                          b0 * E_, MRC, 2);
        }
    } else {
        for (int b = 0; b < B_; ++b) {
            const float* featb = feat + (size_t)b * N_ * OUT_;
            mfma_gemm_k<0, false, false, false, false, 0><<<dim3((UVW_ + 127) / 128, N_ / 128), 256, 0, stream>>>(
                featb, nullptr, uvwt, nullptr, uv, nullptr, N_, UVW_, OUT_, zbuf,
                nullptr, nullptr);
            pair_fuse_k<<<(E_ * 100 + 255) / 256, 256, 0, stream>>>(
                uv, h_b1, src0, dst0, p1, -1, E_);
            mfma_gemm_k<1, true, true, false, false, 0><<<dim3((OUT_ + 127) / 128, E_ / 128), 256, 0, stream>>>(
                nullptr, p1, hw2t, h_b2, p2, nullptr, E_, OUT_, PAIR_, zbuf,
                nullptr, nullptr);
            head3_k<<<(E_ + 15) / 16, 256, 0, stream>>>(p2, h_w3, h_b3, out,
                                                        b * E_, E_);
        }
    }
}

// Round 11
// 1514.302 us; speedup vs baseline: 1.1950x; 1.0387x over previous
//
#include <hip/hip_runtime.h>
#include <hip/hip_bf16.h>

typedef unsigned short u16;   // bf16 bits
typedef __attribute__((ext_vector_type(8))) short bf16x8;   // MFMA A/B frag
typedef __attribute__((ext_vector_type(4))) float f32x4;    // MFMA C/D frag

#define B_   32
#define N_   1024
#define E_   16384
#define ET_  17408            // E_ + N_ self-loops
#define IN_DIM 768
#define HID  512
#define OUT_ 400
#define PAIR_ 800
#define UVW_ 1600             // U(800) ++ V(800) per node
#define FEAT_ELEMS 13107200   // B_*N_*OUT_
#define MAXD 128
#define NPAN 13               // ceil(800/64) K-panels

__device__ __forceinline__ float u2f(u16 u) {
    union { unsigned int i; float f; } v; v.i = ((unsigned int)u) << 16; return v.f;
}
__device__ __forceinline__ u16 f2u(float f) {
    __hip_bfloat16 h = __float2bfloat16(f);   // RNE, HW cvt on gfx950
    return *(u16*)&h;
}
__device__ __forceinline__ unsigned int pack2(float a, float b) {
    return (unsigned int)f2u(a) | ((unsigned int)f2u(b) << 16);
}

__device__ __forceinline__ float gelu_f(float x) {
    const float c = 0.7978845608028654f;          // sqrt(2/pi)
    float u = c * (x + 0.044715f * x * x * x);
    float t = 2.0f / (1.0f + __expf(-2.0f * u)) - 1.0f;   // tanh(u), overflow-safe
    return 0.5f * x * (1.0f + t);
}

// async global->LDS, 16 B per lane; LDS dest is wave-uniform base + lane*16
__device__ __forceinline__ void load_lds16(const void* g, void* l) {
    __builtin_amdgcn_global_load_lds(
        (const __attribute__((address_space(1))) void*)g,
        (__attribute__((address_space(3))) void*)l, 16, 0, 0);
}

// ---------------------------------------------------------------------------
// Fused weight prep (1 launch, was 5): bf16 transposes of all weights.
//  j0 w1t[512][768]  j1 w2t[400][512]  j2 gwt[400][400]
//  j3 uvwt[1600][400] (h_w1 halves split)  j4 hw2t[400][800]
// ---------------------------------------------------------------------------
__global__ __launch_bounds__(256)
void wprep_k(const float* __restrict__ enc_w1, const float* __restrict__ enc_w2,
             const float* __restrict__ gat_w,  const float* __restrict__ h_w1,
             const float* __restrict__ h_w2,
             u16* __restrict__ w1t, u16* __restrict__ w2t, u16* __restrict__ gwt,
             u16* __restrict__ uvwt, u16* __restrict__ hw2t)
{
    int i = blockIdx.x * 256 + threadIdx.x;
    if (i < 393216) {                                   // w1t: K=768,N=512
        int n = i / IN_DIM, k = i - n * IN_DIM;
        w1t[i] = f2u(enc_w1[(size_t)k * HID + n]);
        return;
    }
    i -= 393216;
    if (i < 204800) {                                   // w2t: K=512,N=400
        int n = i / HID, k = i - n * HID;
        w2t[i] = f2u(enc_w2[(size_t)k * OUT_ + n]);
        return;
    }
    i -= 204800;
    if (i < 160000) {                                   // gwt: K=400,N=400
        int n = i / OUT_, k = i - n * OUT_;
        gwt[i] = f2u(gat_w[(size_t)k * OUT_ + n]);
        return;
    }
    i -= 160000;
    if (i < 640000) {                                   // uvwt [1600][400]
        int n = i / OUT_, k = i - n * OUT_;
        int row = (n >= PAIR_) ? OUT_ + k : k;
        int col = (n >= PAIR_) ? n - PAIR_ : n;
        uvwt[i] = f2u(h_w1[(size_t)row * PAIR_ + col]);
        return;
    }
    i -= 640000;
    if (i < 320000) {                                   // hw2t: K=800,N=400
        int n = i / PAIR_, k = i - n * PAIR_;
        hw2t[i] = f2u(h_w2[(size_t)k * OUT_ + n]);
    }
}

// f32 -> bf16 bulk convert, 8 elems/lane
__global__ void f2b_k(const float* __restrict__ X, u16* __restrict__ Y, int n8)
{
    int i = blockIdx.x * 256 + threadIdx.x;
    if (i >= n8) return;
    const float4* p = (const float4*)X + (size_t)i * 2;
    float4 a = p[0], b = p[1];
    uint4 o;
    o.x = pack2(a.x, a.y); o.y = pack2(a.z, a.w);
    o.z = pack2(b.x, b.y); o.w = pack2(b.z, b.w);
    ((uint4*)Y)[i] = o;
}

// ---------------------------------------------------------------------------
// MFMA GEMM: C[M,N] = act(A[M,K] @ W[K,N] + bias), f32 accumulate.
// SHAPE 0: 128x128, BK=64, 4 waves (small-mode legacy; ASRC 0/1)
// SHAPE 1: 256x256, BK=64, 8 waves, wave=64x128, LDS 128KB dbuf.
// ASRC: 0 = f32 A (VGPR cvt staging, SHAPE0 only)
//       1 = bf16 A row-major [M][K] (async global_load_lds)
//       3 = bf16 A K-PANEL [K/64][M][64] (contiguous per-window slabs)
// 2-phase pipeline: stage(next) BEFORE compute; counted vmcnt(8); raw barrier.
// T1 XCD-chunked bijective swizzle (m204) for L2 locality of A panels.
// FUSE_H3: no C store; contract tile with w3 [N][3] after gelu(.+bias):
// shfl over lm, LDS-combine wn-wave pairs, non-atomic part[bnIdx][row][3];
// red3_k sums gx slices + b3.
// LDS XOR swizzle phys_chunk=log_chunk^(row&7): global_load_lds contiguity
// AND conflict-free ds_read_b128 (m136). OOB lanes read zbuf.
// ---------------------------------------------------------------------------
template<int ASRC, bool DO_GELU, bool HAS_BIAS, bool OUT_F32, bool FUSE_H3, int SHAPE>
__global__ __launch_bounds__(SHAPE >= 1 ? 512 : 256, 2)
void mfma_gemm_k(const float* __restrict__ Af, const u16* __restrict__ Ab,
                 const u16* __restrict__ Wt, const float* __restrict__ bias,
                 u16* __restrict__ Cb, float* __restrict__ Cf,
                 int M, int N, int K,
                 const u16* __restrict__ zbuf,
                 const float* __restrict__ w3p, float* __restrict__ partp)
{
    static_assert(SHAPE == 0 || ASRC >= 1, "wide shapes need bf16 async staging");
    constexpr int BM  = (SHAPE == 1) ? 256 : 128;
    constexpr int BN  = (SHAPE == 1) ? 256 : 128;
    constexpr int UN  = (SHAPE == 1) ? 8 : 4;      // 16-col frags per wave
    constexpr int CW  = 2;                         // col-waves per row-group

    __shared__ __align__(16) u16 As[2][BM * 64];
    __shared__ __align__(16) u16 Bs[2][BN * 64];
    const int tid  = threadIdx.x;
    // --- T1 bijective XCD swizzle ---
    const int gx   = gridDim.x;
    const int nwg  = gx * gridDim.y;
    const int orig = blockIdx.y * gx + blockIdx.x;
    const int qc   = nwg >> 3, rc = nwg & 7;
    const int xcd  = orig & 7, lid = orig >> 3;
    const int wg   = ((xcd < rc) ? xcd * (qc + 1) : rc * (qc + 1) + (xcd - rc) * qc) + lid;
    const int bnIdx= wg % gx;
    const int bm   = (wg / gx) * BM;
    const int bn   = bnIdx * BN;
    const int wave = tid >> 6;
    const int lane = tid & 63;
    const int wm   = (wave >> 1) * 64;
    const int wn   = (SHAPE == 1) ? (wave & 1) * 128 : (wave & 1) * 64;
    const int lm   = lane & 15;
    const int lq   = lane >> 4;
    const int lb   = lm & 7;
    // staging lane geometry: instr c4 covers rows wave*32+c4*8 .. +7
    const int l8 = lane >> 3;            // row within 8-row group
    const int cl = (lane & 7) ^ l8;      // pre-swizzled 8-elem chunk (0..7)

    // per-c4 row metadata (wave*32 row groups cover BM rows)
    size_t arow[4]; size_t brow[4]; bool bok[4];
    #pragma unroll
    for (int c4 = 0; c4 < 4; ++c4) {
        int rt = wave * 32 + c4 * 8 + l8;          // tile row
        if (ASRC == 1) arow[c4] = (size_t)(bm + rt) * K;
        if (ASRC == 3) arow[c4] = (size_t)(bm + rt) * 64;   // offset in panel
        int n = bn + rt;
        bok[c4] = (n < N);
        brow[c4] = (size_t)(n < N ? n : 0) * K;
    }
    // VGPR-staging geometry (ASRC 0, SHAPE 0 only)
    const int vrow = tid >> 1, vhalf = tid & 1;

    f32x4 acc[4][UN] = {};
    const int NT = (K + 63) >> 6;

    if (ASRC >= 1) {
        auto stage = [&](int buf, int k0) {
            int kk = k0 + cl * 8;
            if (ASRC == 3) {
                const u16* pan = Ab + (size_t)(k0 >> 6) * M * 64;
                #pragma unroll
                for (int c4 = 0; c4 < 4; ++c4) {
                    const u16* ga = (kk < K) ? pan + arow[c4] + cl * 8 : zbuf;
                    load_lds16(ga, (char*)As[buf] + (wave * 32 + c4 * 8) * 128);
                }
            } else {
                #pragma unroll
                for (int c4 = 0; c4 < 4; ++c4) {
                    const u16* ga = (kk < K) ? Ab + arow[c4] + kk : zbuf;
                    load_lds16(ga, (char*)As[buf] + (wave * 32 + c4 * 8) * 128);
                }
            }
            #pragma unroll
            for (int c4 = 0; c4 < 4; ++c4) {
                const u16* gb = (bok[c4] && kk < K) ? Wt + brow[c4] + kk : zbuf;
                load_lds16(gb, (char*)Bs[buf] + (wave * 32 + c4 * 8) * 128);
            }
        };
        stage(0, 0);
        int cur = 0;
        for (int it = 0; it < NT; ++it) {
            const bool last = (it == NT - 1);
            if (!last) stage(cur ^ 1, (it + 1) * 64);
            if (!last) asm volatile("s_waitcnt vmcnt(8)" ::: "memory");
            else       asm volatile("s_waitcnt vmcnt(0)" ::: "memory");
            __builtin_amdgcn_s_barrier();
            const char* Abase = (const char*)As[cur];
            const char* Bbase = (const char*)Bs[cur];
            #pragma unroll
            for (int kh = 0; kh < 2; ++kh) {
                bf16x8 af[4], bfr[UN];
                #pragma unroll
                for (int t = 0; t < 4; ++t)
                    af[t] = *(const bf16x8*)(Abase +
                            (wm + t * 16 + lm) * 128 + (((kh * 4 + lq) ^ lb) * 16));
                #pragma unroll
                for (int u = 0; u < UN; ++u)
                    bfr[u] = *(const bf16x8*)(Bbase +
                            (wn + u * 16 + lm) * 128 + (((kh * 4 + lq) ^ lb) * 16));
                #pragma unroll
                for (int t = 0; t < 4; ++t)
                    #pragma unroll
                    for (int u = 0; u < UN; ++u)
                        acc[t][u] = __builtin_amdgcn_mfma_f32_16x16x32_bf16(
                            af[t], bfr[u], acc[t][u], 0, 0, 0);
            }
            asm volatile("" ::: "memory");
            __builtin_amdgcn_s_barrier();
            cur ^= 1;
        }
    } else {
        for (int k0 = 0; k0 < K; k0 += 64) {
            // ---- stage A (VGPR cvt, SHAPE0 only)
            #pragma unroll
            for (int c = 0; c < 4; ++c) {
                int c_log = vhalf * 4 + c;
                int kk = k0 + c_log * 8;
                uint4 wv = make_uint4(0, 0, 0, 0);
                if (kk < K) {
                    const float* p = Af + (size_t)(bm + vrow) * K + kk;
                    float4 v0 = *(const float4*)p;
                    float4 v1 = *(const float4*)(p + 4);
                    wv.x = pack2(v0.x, v0.y); wv.y = pack2(v0.z, v0.w);
                    wv.z = pack2(v1.x, v1.y); wv.w = pack2(v1.z, v1.w);
                }
                int pc = c_log ^ (vrow & 7);
                *(uint4*)((char*)As[0] + vrow * 128 + pc * 16) = wv;
            }
            // ---- stage B (async)
            {
                int kk = k0 + cl * 8;
                #pragma unroll
                for (int c4 = 0; c4 < 4; ++c4) {
                    const u16* gb = (bok[c4] && kk < K) ? Wt + brow[c4] + kk : zbuf;
                    load_lds16(gb, (char*)Bs[0] + (wave * 32 + c4 * 8) * 128);
                }
            }
            __syncthreads();
            #pragma unroll
            for (int kh = 0; kh < 2; ++kh) {
                bf16x8 af[4], bfr[UN];
                #pragma unroll
                for (int t = 0; t < 4; ++t)
                    af[t] = *(const bf16x8*)((const char*)As[0] +
                            (wm + t * 16 + lm) * 128 + (((kh * 4 + lq) ^ lb) * 16));
                #pragma unroll
                for (int u = 0; u < UN; ++u)
                    bfr[u] = *(const bf16x8*)((const char*)Bs[0] +
                            (wn + u * 16 + lm) * 128 + (((kh * 4 + lq) ^ lb) * 16));
                #pragma unroll
                for (int t = 0; t < 4; ++t)
                    #pragma unroll
                    for (int u = 0; u < UN; ++u)
                        acc[t][u] = __builtin_amdgcn_mfma_f32_16x16x32_bf16(
                            af[t], bfr[u], acc[t][u], 0, 0, 0);
            }
            __syncthreads();
        }
    }

    // ---- fused head3 epilogue: part[bnIdx][row] = gelu(p2_tile) @ w3
    if (FUSE_H3) {
        float w3c[UN][3]; float bvv[UN];
        #pragma unroll
        for (int u = 0; u < UN; ++u) {
            int col = bn + wn + u * 16 + lm;
            bool ok = (col < N);
            bvv[u]    = ok ? bias[col] : 0.f;
            w3c[u][0] = ok ? w3p[col * 3 + 0] : 0.f;
            w3c[u][1] = ok ? w3p[col * 3 + 1] : 0.f;
            w3c[u][2] = ok ? w3p[col * 3 + 2] : 0.f;
        }
        float* red = (float*)As;         // [waves][64 rows][3] floats, As dead
        #pragma unroll
        for (int t = 0; t < 4; ++t) {
            #pragma unroll
            for (int r = 0; r < 4; ++r) {
                float s0 = 0.f, s1 = 0.f, s2 = 0.f;
                #pragma unroll
                for (int u = 0; u < UN; ++u) {
                    float v = gelu_f(acc[t][u][r] + bvv[u]);
                    s0 += v * w3c[u][0];
                    s1 += v * w3c[u][1];
                    s2 += v * w3c[u][2];
                }
                #pragma unroll
                for (int off = 8; off; off >>= 1) {
                    s0 += __shfl_xor(s0, off);
                    s1 += __shfl_xor(s1, off);
                    s2 += __shfl_xor(s2, off);
                }
                if (lm == 0) {
                    int lr = t * 16 + lq * 4 + r;            // 0..63 within wave
                    float* d = red + (wave * 64 + lr) * 3;
                    d[0] = s0; d[1] = s1; d[2] = s2;
                }
            }
        }
        __syncthreads();
        if ((wave & (CW - 1)) == 0) {     // lead wave of each row-group pair
            int lr = lane;
            int rowg = bm + wm + lr;
            float s0 = 0.f, s1 = 0.f, s2 = 0.f;
            #pragma unroll
            for (int w = 0; w < CW; ++w) {
                float* a = red + ((wave + w) * 64 + lr) * 3;
                s0 += a[0]; s1 += a[1]; s2 += a[2];
            }
            float* d = partp + ((size_t)bnIdx * M + rowg) * 3;
            d[0] = s0; d[1] = s1; d[2] = s2;
        }
        return;
    }

    // ---- epilogue: C col = lane&15, row = quad*4 + reg (verified m89/m91)
    #pragma unroll
    for (int u = 0; u < UN; ++u) {
        int col = bn + wn + u * 16 + lm;
        if (col >= N) continue;
        float bv = HAS_BIAS ? bias[col] : 0.f;
        #pragma unroll
        for (int t = 0; t < 4; ++t) {
            #pragma unroll
            for (int r = 0; r < 4; ++r) {
                int rowg = bm + wm + t * 16 + lq * 4 + r;
                float v = acc[t][u][r] + bv;
                if (DO_GELU) v = gelu_f(v);
                if (OUT_F32) {
                    Cf[(size_t)rowg * N + col] = v;
                    if (Cb) Cb[(size_t)rowg * N + col] = f2u(v);  // dual write
                } else {
                    Cb[(size_t)rowg * N + col] = f2u(v);
                }
            }
        }
    }
}

// ---------------------------------------------------------------------------
// Partial reduce: pred[row_base+r,:] = b3 + sum_{s<ns} part[s][r][:]
// ---------------------------------------------------------------------------
__global__ __launch_bounds__(256)
void red3_k(const float* __restrict__ part, const float* __restrict__ b3,
            float* __restrict__ out, int row_base, int Mr, int ns)
{
    int r = blockIdx.x * 256 + threadIdx.x;
    if (r >= Mr) return;
    float s0 = b3[0], s1 = b3[1], s2 = b3[2];
    for (int s = 0; s < ns; ++s) {
        const float* p = part + ((size_t)s * Mr + r) * 3;
        s0 += p[0]; s1 += p[1]; s2 += p[2];
    }
    float* d = out + (size_t)FEAT_ELEMS + (size_t)(row_base + r) * 3;
    d[0] = s0; d[1] = s1; d[2] = s2;
}

// ---------------------------------------------------------------------------
// Pair fuse, K-PANEL output: p1k[p][mrows][64] = gelu(U[src]+V[dst]+b1).
// rsh = log2(mrows) (15 for CB=2, 16 for CB=4). idx = (p<<rsh | r)*8 + s ->
// consecutive threads write consecutive 16B panel chunks (streaming) and
// read 128B-coalesced UV row slices. Cols >= 800 skipped (GEMM2 zbuf-guards).
// ---------------------------------------------------------------------------
__global__ __launch_bounds__(256)
void pair_fuse_kp(const u16* __restrict__ UV, const float* __restrict__ b1,
                  const int* __restrict__ src0, const int* __restrict__ dst0,
                  u16* __restrict__ p1k, int b0, int rsh)
{
    unsigned idx = blockIdx.x * 256u + threadIdx.x;
    unsigned s = idx & 7u;
    unsigned r = (idx >> 3) & ((1u << rsh) - 1u);
    unsigned p = idx >> (3 + rsh);
    if (p >= NPAN) return;
    int k0 = (int)(p * 64 + s * 8);
    if (k0 >= PAIR_) return;
    int e = (int)(r & (E_ - 1));
    int b = b0 + (int)(r >> 14);
    int gs = (b << 10) + src0[e];
    int gd = (b << 10) + dst0[e];
    uint4 qu = *(const uint4*)(UV + (size_t)gs * UVW_ + k0);
    uint4 qv = *(const uint4*)(UV + (size_t)gd * UVW_ + PAIR_ + k0);
    float4 bva = *(const float4*)(b1 + k0);
    float4 bvb = *(const float4*)(b1 + k0 + 4);
    float bb[8] = {bva.x, bva.y, bva.z, bva.w, bvb.x, bvb.y, bvb.z, bvb.w};
    unsigned int uu[4] = {qu.x, qu.y, qu.z, qu.w};
    unsigned int vv[4] = {qv.x, qv.y, qv.z, qv.w};
    uint4 o; unsigned int* op = (unsigned int*)&o;
    #pragma unroll
    for (int q = 0; q < 4; ++q) {
        float a0 = u2f((u16)(uu[q] & 0xffff)) + u2f((u16)(vv[q] & 0xffff)) + bb[2*q];
        float a1 = u2f((u16)(uu[q] >> 16))    + u2f((u16)(vv[q] >> 16))    + bb[2*q+1];
        op[q] = pack2(gelu_f(a0), gelu_f(a1));
    }
    *(uint4*)(p1k + (((size_t)p << rsh) + r) * 64 + s * 8) = o;
}

// ---------------------------------------------------------------------------
// Pair fuse (small mode only): p1[r,:] = gelu(U[src] + V[dst] + b1).
// ---------------------------------------------------------------------------
__global__ __launch_bounds__(256)
void pair_fuse_k(const u16* __restrict__ UV, const float* __restrict__ b1,
                 const int* __restrict__ src0, const int* __restrict__ dst0,
                 u16* __restrict__ p1, int b0, int nrows)
{
    unsigned idx = blockIdx.x * 256u + threadIdx.x;
    unsigned total = (unsigned)nrows * 100u;
    if (idx >= total) return;
    unsigned r  = (unsigned)(((unsigned long long)idx * 1374389535ull) >> 37); // /100
    unsigned c8 = idx - r * 100u;
    int e = r & (E_ - 1);
    int gs, gd;
    if (b0 >= 0) {
        int b = b0 + (int)(r >> 14);
        gs = (b << 10) + src0[e];
        gd = (b << 10) + dst0[e];
    } else {
        gs = src0[e]; gd = dst0[e];
    }
    uint4 qu = *(const uint4*)(UV + (size_t)gs * UVW_ + c8 * 8);
    uint4 qv = *(const uint4*)(UV + (size_t)gd * UVW_ + PAIR_ + c8 * 8);
    float4 bva = *(const float4*)(b1 + c8 * 8);
    float4 bvb = *(const float4*)(b1 + c8 * 8 + 4);
    float bb[8] = {bva.x, bva.y, bva.z, bva.w, bvb.x, bvb.y, bvb.z, bvb.w};
    unsigned int uu[4] = {qu.x, qu.y, qu.z, qu.w};
    unsigned int vv[4] = {qv.x, qv.y, qv.z, qv.w};
    uint4 o; unsigned int* op = (unsigned int*)&o;
    #pragma unroll
    for (int q = 0; q < 4; ++q) {
        float a0 = u2f((u16)(uu[q] & 0xffff)) + u2f((u16)(vv[q] & 0xffff)) + bb[2*q];
        float a1 = u2f((u16)(uu[q] >> 16))    + u2f((u16)(vv[q] >> 16))    + bb[2*q+1];
        op[q] = pack2(gelu_f(a0), gelu_f(a1));
    }
    *(uint4*)(p1 + (size_t)r * PAIR_ + c8 * 8) = o;
}

// ---------------------------------------------------------------------------
// Attention scores
// ---------------------------------------------------------------------------
__global__ __launch_bounds__(256)
void scores_k(const u16* __restrict__ wh, const float* __restrict__ att_s,
              const float* __restrict__ att_d, float* __restrict__ a_s,
              float* __restrict__ a_d)
{
    int n = blockIdx.x * 4 + (threadIdx.x >> 6);
    int lane = threadIdx.x & 63;
    const u16* row = wh + (size_t)n * OUT_;
    float as0 = 0, as1 = 0, ad0 = 0, ad1 = 0;
    for (int f = lane; f < OUT_; f += 64) {
        float v = u2f(row[f]);
        float s = att_s[f];
        float d = att_d[f];
        if (f < 200) { as0 += v * s; ad0 += v * d; }
        else         { as1 += v * s; ad1 += v * d; }
    }
    for (int off = 32; off; off >>= 1) {
        as0 += __shfl_xor(as0, off); as1 += __shfl_xor(as1, off);
        ad0 += __shfl_xor(ad0, off); ad1 += __shfl_xor(ad1, off);
    }
    if (lane == 0) {
        a_s[(size_t)n * 2 + 0] = as0; a_s[(size_t)n * 2 + 1] = as1;
        a_d[(size_t)n * 2 + 0] = ad0; a_d[(size_t)n * 2 + 1] = ad1;
    }
}

// ---------------------------------------------------------------------------
// CSR build (edges shared across batches; incl. self-loops)
// ---------------------------------------------------------------------------
__global__ void csr_count_k(const int* __restrict__ edges, int* __restrict__ deg)
{
    int et = blockIdx.x * blockDim.x + threadIdx.x;
    if (et >= ET_) return;
    int dst = (et < E_) ? edges[E_ + et] : (et - E_);
    atomicAdd(&deg[dst], 1);
}

__global__ __launch_bounds__(1024)
void csr_scan_k(const int* __restrict__ deg, int* __restrict__ row_ptr,
                int* __restrict__ cnt)
{
    __shared__ int s[1024];
    int t = threadIdx.x;
    int d = deg[t];
    s[t] = d;
    __syncthreads();
    for (int off = 1; off < 1024; off <<= 1) {
        int v = (t >= off) ? s[t - off] : 0;
        __syncthreads();
        s[t] += v;
        __syncthreads();
    }
    row_ptr[t] = s[t] - d;   // exclusive
    cnt[t] = s[t] - d;
    if (t == 1023) row_ptr[1024] = s[t];
}

__global__ void csr_fill_k(const int* __restrict__ edges, int* __restrict__ cnt,
                           int* __restrict__ col_src)
{
    int et = blockIdx.x * blockDim.x + threadIdx.x;
    if (et >= ET_) return;
    int src, dst;
    if (et < E_) { src = edges[et]; dst = edges[E_ + et]; }
    else         { src = et - E_;  dst = src; }
    int pos = atomicAdd(&cnt[dst], 1);
    col_src[pos] = src;
}

// ---------------------------------------------------------------------------
// Fused GAT softmax + aggregation + residual, in place on f32 feat (d_out).
// ---------------------------------------------------------------------------
__global__ __launch_bounds__(256)
void gat_k(const u16* __restrict__ wh,
           const float* __restrict__ a_s, const float* __restrict__ a_d,
           const int* __restrict__ row_ptr, const int* __restrict__ col_src,
           const float* __restrict__ gat_b, float* __restrict__ feat,
           u16* __restrict__ featb16)
{
    int gn = blockIdx.x;                  // b*1024 + n
    int b = gn >> 10, n = gn & 1023;
    int tid = threadIdx.x;
    __shared__ float s_ee[2][MAXD];
    __shared__ int   s_src[MAXD];
    __shared__ float s_misc[6];           // m0,m1,invz0,invz1,ad0,ad1
    __shared__ float s_part[4][50][9];    // +1 pad col: spread banks
    int start = row_ptr[n];
    int deg = row_ptr[n + 1] - start;

    if (tid < 64) {
        int lane = tid;
        float ad0 = a_d[(size_t)gn * 2 + 0];
        float ad1 = a_d[(size_t)gn * 2 + 1];
        float m0 = -1e30f, m1 = -1e30f;
        for (int j = lane; j < deg; j += 64) {
            int gs = (b << 10) + col_src[start + j];
            float e0 = a_s[(size_t)gs * 2 + 0] + ad0; e0 = (e0 > 0.f) ? e0 : 0.2f * e0;
            float e1 = a_s[(size_t)gs * 2 + 1] + ad1; e1 = (e1 > 0.f) ? e1 : 0.2f * e1;
            if (j < MAXD) { s_ee[0][j] = e0; s_ee[1][j] = e1; s_src[j] = gs; }
            m0 = fmaxf(m0, e0); m1 = fmaxf(m1, e1);
        }
        for (int off = 32; off; off >>= 1) {
            m0 = fmaxf(m0, __shfl_xor(m0, off));
            m1 = fmaxf(m1, __shfl_xor(m1, off));
        }
        float z0 = 0.f, z1 = 0.f;
        for (int j = lane; j < deg; j += 64) {
            float e0, e1;
            if (j < MAXD) { e0 = s_ee[0][j]; e1 = s_ee[1][j]; }
            else {
                int gs = (b << 10) + col_src[start + j];
                e0 = a_s[(size_t)gs * 2 + 0] + ad0; e0 = (e0 > 0.f) ? e0 : 0.2f * e0;
                e1 = a_s[(size_t)gs * 2 + 1] + ad1; e1 = (e1 > 0.f) ? e1 : 0.2f * e1;
            }
            float t0 = __expf(e0 - m0), t1 = __expf(e1 - m1);
            if (j < MAXD) { s_ee[0][j] = t0; s_ee[1][j] = t1; }
            z0 += t0; z1 += t1;
        }
        for (int off = 32; off; off >>= 1) {
            z0 += __shfl_xor(z0, off);
            z1 += __shfl_xor(z1, off);
        }
        if (lane == 0) {
            s_misc[0] = m0; s_misc[1] = m1;
            s_misc[2] = (z0 > 0.f) ? 1.f / z0 : 0.f;
            s_misc[3] = (z1 > 0.f) ? 1.f / z1 : 0.f;
            s_misc[4] = ad0; s_misc[5] = ad1;
        }
    }
    __syncthreads();

    int wv = tid >> 6, ln = tid & 63;
    if (ln < 50) {
        int h = (ln >= 25);
        float m = s_misc[h], ad = s_misc[4 + h];
        float acc[8] = {};
        for (int j = wv; j < deg; j += 4) {
            float w; int gs;
            if (j < MAXD) { w = s_ee[h][j]; gs = s_src[j]; }
            else {
                gs = (b << 10) + col_src[start + j];
                float e = a_s[(size_t)gs * 2 + h] + ad;
                e = (e > 0.f) ? e : 0.2f * e;
                w = __expf(e - m);
            }
            uint4 q = *(const uint4*)(wh + (size_t)gs * OUT_ + ln * 8);
            acc[0] += w * u2f((u16)(q.x & 0xffff));
            acc[1] += w * u2f((u16)(q.x >> 16));
            acc[2] += w * u2f((u16)(q.y & 0xffff));
            acc[3] += w * u2f((u16)(q.y >> 16));
            acc[4] += w * u2f((u16)(q.z & 0xffff));
            acc[5] += w * u2f((u16)(q.z >> 16));
            acc[6] += w * u2f((u16)(q.w & 0xffff));
            acc[7] += w * u2f((u16)(q.w >> 16));
        }
        #pragma unroll
        for (int k = 0; k < 8; ++k) s_part[wv][ln][k] = acc[k];
    }
    __syncthreads();
    if (tid < 50) {
        int h = (tid >= 25);
        float iz = s_misc[2 + h];
        size_t base = (size_t)gn * OUT_ + tid * 8;
        float4 f0 = *(const float4*)(feat + base);
        float4 f1 = *(const float4*)(feat + base + 4);
        float fv[8] = { f0.x, f0.y, f0.z, f0.w, f1.x, f1.y, f1.z, f1.w };
        float o[8];
        #pragma unroll
        for (int k = 0; k < 8; ++k) {
            float s = s_part[0][tid][k] + s_part[1][tid][k] +
                      s_part[2][tid][k] + s_part[3][tid][k];
            o[k] = fv[k] + s * iz + gat_b[tid * 8 + k];
        }
        *(float4*)(feat + base)     = make_float4(o[0], o[1], o[2], o[3]);
        *(float4*)(feat + base + 4) = make_float4(o[4], o[5], o[6], o[7]);
        if (featb16) {
            uint4 bq;
            bq.x = pack2(o[0], o[1]); bq.y = pack2(o[2], o[3]);
            bq.z = pack2(o[4], o[5]); bq.w = pack2(o[6], o[7]);
            *(uint4*)(featb16 + base) = bq;
        }
    }
}

// ---------------------------------------------------------------------------
// Final tiny GEMM (small-mode only): pred[e,:] = p2[e,:] @ w3[400,3] + b3.
// ---------------------------------------------------------------------------
__global__ __launch_bounds__(256)
void head3_k(const u16* __restrict__ p2, const float* __restrict__ w3,
             const float* __restrict__ b3, float* __restrict__ out,
             int row_base, int nrows)
{
    int wv = threadIdx.x >> 6, lane = threadIdx.x & 63;
    float w3r[24];
    if (lane < 50) {
        #pragma unroll
        for (int q = 0; q < 6; ++q) {
            float4 v = *(const float4*)(w3 + lane * 24 + q * 4);
            w3r[q * 4 + 0] = v.x; w3r[q * 4 + 1] = v.y;
            w3r[q * 4 + 2] = v.z; w3r[q * 4 + 3] = v.w;
        }
    }
    int e0 = blockIdx.x * 16 + wv * 4;
    for (int ei = 0; ei < 4; ++ei) {
        int e = e0 + ei;
        if (e >= nrows) break;
        float s0 = 0, s1 = 0, s2 = 0;
        if (lane < 50) {
            uint4 q = *(const uint4*)(p2 + (size_t)e * OUT_ + lane * 8);
            float f[8];
            f[0] = u2f((u16)(q.x & 0xffff)); f[1] = u2f((u16)(q.x >> 16));
            f[2] = u2f((u16)(q.y & 0xffff)); f[3] = u2f((u16)(q.y >> 16));
            f[4] = u2f((u16)(q.z & 0xffff)); f[5] = u2f((u16)(q.z >> 16));
            f[6] = u2f((u16)(q.w & 0xffff)); f[7] = u2f((u16)(q.w >> 16));
            #pragma unroll
            for (int k = 0; k < 8; ++k) {
                s0 += f[k] * w3r[k * 3 + 0];
                s1 += f[k] * w3r[k * 3 + 1];
                s2 += f[k] * w3r[k * 3 + 2];
            }
        }
        for (int off = 32; off; off >>= 1) {
            s0 += __shfl_xor(s0, off);
            s1 += __shfl_xor(s1, off);
            s2 += __shfl_xor(s2, off);
        }
        if (lane == 0) {
            size_t o = (size_t)FEAT_ELEMS + (size_t)(row_base + e) * 3;
            out[o + 0] = s0 + b3[0];
            out[o + 1] = s1 + b3[1];
            out[o + 2] = s2 + b3[2];
        }
    }
}

extern "C" void kernel_launch(void* const* d_in, const int* in_sizes, int n_in,
                              void* d_out, int out_size, void* d_ws, size_t ws_size,
                              hipStream_t stream)
{
    const float* patch  = (const float*)d_in[0];
    const int*   edges  = (const int*)d_in[1];
    const float* enc_w1 = (const float*)d_in[2];
    const float* enc_b1 = (const float*)d_in[3];
    const float* enc_w2 = (const float*)d_in[4];
    const float* enc_b2 = (const float*)d_in[5];
    const float* gat_w  = (const float*)d_in[6];
    const float* att_s  = (const float*)d_in[7];
    const float* att_d  = (const float*)d_in[8];
    const float* gat_b  = (const float*)d_in[9];
    const float* h_w1   = (const float*)d_in[10];
    const float* h_b1   = (const float*)d_in[11];
    const float* h_w2   = (const float*)d_in[12];
    const float* h_b2   = (const float*)d_in[13];
    const float* h_w3   = (const float*)d_in[14];
    const float* h_b3   = (const float*)d_in[15];
    float* out  = (float*)d_out;
    float* feat = out;                          // f32 [32768,400] in d_out
    char*  ws   = (char*)d_ws;

    const int* src0 = edges;
    const int* dst0 = edges + E_;

    // --- mode select from ws_size (deterministic; graph-capture safe) ------
    // big-mode layout:
    //   [0,R0)            enc1 bf16; featb16 overlays (dead enc1);
    //                     head-phase: part f32 [2][CBh*E][3] (<=1.6MB)
    //   [R0, R0+26.2MB)   whb bf16 (dead after gat_k)
    //   [R0+26.2,+52.4MB) encb16 bf16 (consumed by GAT linear)
    //   [R0, R0+UVSZ)     UV bf16 [32768,1600] (overlays whb+encb16, after gat)
    //   [R0+UVSZ, +P1K)   p1k K-panel [13][CBh*E][64] bf16 (55/109MB);
    //                     patchb16 (50.3MB) overlays (dead before head)
    //   [ws_size-TAIL,..) weights + scores + CSR + zbuf
    const size_t R0 = 33554432ull, TAIL = 4194304ull;
    const size_t UVSZ = 104857600ull;            // 32768*1600*2
    const size_t P1K4 = (size_t)NPAN * 65536 * 64 * 2;  // 109,051,904
    const size_t P1K2 = (size_t)NPAN * 32768 * 64 * 2;  //  54,525,952
    int CBh = 0;
    if      (ws_size >= R0 + UVSZ + P1K4 + TAIL) CBh = 4;
    else if (ws_size >= R0 + UVSZ + P1K2 + TAIL) CBh = 2;
    const bool big = (CBh >= 2);
    const int MRC  = CBh * E_;                   // rows per head chunk
    const int RSH  = (CBh == 4) ? 16 : 15;       // log2(MRC)

    u16 *enc1, *whb, *p1, *p2, *featb16, *uv, *w1t, *w2t, *gwt, *uvwt, *hw2t;
    u16 *patchb16, *encb16, *p1k;
    float *a_s, *a_d, *part; int *deg;
    if (big) {
        enc1    = (u16*)ws;
        featb16 = (u16*)ws;                     // overlays enc1 (dead)
        part    = (float*)ws;                   // head-phase reuse (featb16 dead)
        whb     = (u16*)(ws + R0);
        uv      = (u16*)(ws + R0);              // overlays whb (dead after gat)
        encb16  = (u16*)(ws + R0 + 26214400ull);// enc bf16, dead before UV GEMM
        p1k     = (u16*)(ws + R0 + UVSZ);
        patchb16= (u16*)(ws + R0 + UVSZ);       // overlays p1k (dead before head)
        p1      = nullptr;
        p2      = nullptr;
        size_t tb = (ws_size - TAIL) & ~(size_t)255;
        w1t  = (u16*)(ws + tb);
        w2t  = (u16*)(ws + tb + 786432);
        gwt  = (u16*)(ws + tb + 1196032);
        uvwt = (u16*)(ws + tb + 1516032);       // 1600*400*2 = 1,280,000
        hw2t = (u16*)(ws + tb + 2796032);
        a_s  = (float*)(ws + tb + 3436032);
        a_d  = (float*)(ws + tb + 3698176);
        deg  = (int*)(ws + tb + 3960320);
    } else {
        enc1    = (u16*)ws;                     // sequenced overlays
        whb     = (u16*)ws;
        p1      = (u16*)ws;
        featb16 = nullptr;
        patchb16= nullptr;
        encb16  = nullptr;
        part    = nullptr;
        p1k     = nullptr;
        p2      = (u16*)(ws + 26214400);
        uv      = (u16*)(ws + 39321600);        // 1024*1600*2 = 3,276,800
        w1t  = (u16*)(ws + 42598400);
        w2t  = (u16*)(ws + 43384832);
        gwt  = (u16*)(ws + 43794432);
        uvwt = (u16*)(ws + 44114432);
        hw2t = (u16*)(ws + 45394432);
        a_s  = (float*)(ws + 46034432);
        a_d  = (float*)(ws + 46296576);
        deg  = (int*)(ws + 46558720);
    }
    int* row_ptr = deg + 1024;
    int* cnt     = row_ptr + 1032;
    int* col_src = cnt + 1024;
    u16* zbuf = (u16*)(col_src + 17408);        // 256 B zero scratch (16B aligned)

    hipMemsetAsync(zbuf, 0, 256, stream);

    // fused weight prep (1 launch, was 5)
    wprep_k<<<(1718016 + 255) / 256, 256, 0, stream>>>(
        enc_w1, enc_w2, gat_w, h_w1, h_w2, w1t, w2t, gwt, uvwt, hw2t);

    // CSR by dst (batch-independent)
    hipMemsetAsync(deg, 0, 1024 * sizeof(int), stream);
    csr_count_k<<<(ET_ + 255) / 256, 256, 0, stream>>>(edges, deg);
    csr_scan_k<<<1, 1024, 0, stream>>>(deg, row_ptr, cnt);
    csr_fill_k<<<(ET_ + 255) / 256, 256, 0, stream>>>(edges, cnt, col_src);

    if (big) {
        // patch -> bf16 once (numerics identical: staging already cvt'd)
        f2b_k<<<(B_ * N_ * IN_DIM / 8 + 255) / 256, 256, 0, stream>>>(
            patch, patchb16, B_ * N_ * IN_DIM / 8);
        // encoder: enc1 = gelu(patch @ w1 + b1)   [wide 256x256]
        mfma_gemm_k<1, true, true, false, false, 1><<<dim3(2, (B_ * N_) / 256), 512, 0, stream>>>(
            nullptr, patchb16, w1t, enc_b1, enc1, nullptr, B_ * N_, HID, IN_DIM, zbuf,
            nullptr, nullptr);
        // feat(f32, d_out) + encb16(bf16) = enc1 @ w2 + b2
        mfma_gemm_k<1, false, true, true, false, 1><<<dim3(2, (B_ * N_) / 256), 512, 0, stream>>>(
            nullptr, enc1, w2t, enc_b2, encb16, feat, B_ * N_, OUT_, HID, zbuf,
            nullptr, nullptr);
        // GAT linear: wh = enc(bf16) @ gat_w
        mfma_gemm_k<1, false, false, false, false, 1><<<dim3(2, (B_ * N_) / 256), 512, 0, stream>>>(
            nullptr, encb16, gwt, nullptr, whb, nullptr, B_ * N_, OUT_, OUT_, zbuf,
            nullptr, nullptr);
    } else {
        mfma_gemm_k<0, true, true, false, false, 0><<<dim3(HID / 128, (B_ * N_) / 128), 256, 0, stream>>>(
            patch, nullptr, w1t, enc_b1, enc1, nullptr, B_ * N_, HID, IN_DIM, zbuf,
            nullptr, nullptr);
        mfma_gemm_k<1, false, true, true, false, 0><<<dim3((OUT_ + 127) / 128, (B_ * N_) / 128), 256, 0, stream>>>(
            nullptr, enc1, w2t, enc_b2, nullptr, feat, B_ * N_, OUT_, HID, zbuf,
            nullptr, nullptr);
        mfma_gemm_k<0, false, false, false, false, 0><<<dim3((OUT_ + 127) / 128, (B_ * N_) / 128), 256, 0, stream>>>(
            feat, nullptr, gwt, nullptr, whb, nullptr, B_ * N_, OUT_, OUT_, zbuf,
            nullptr, nullptr);
    }

    scores_k<<<(B_ * N_) / 4, 256, 0, stream>>>(whb, att_s, att_d, a_s, a_d);
    gat_k<<<B_ * N_, 256, 0, stream>>>(whb, a_s, a_d, row_ptr, col_src,
                                       gat_b, feat, featb16);

    // predict head — GEMM1 distributed (UV); pair_fuse writes K-panel p1k;
    // GEMM2 (ASRC=3 panel-streaming A) fused with head3; red3 sums 2 slices.
    if (big) {
        // UV = featb16 @ uvwt  -> bf16 [32768,1600]
        mfma_gemm_k<1, false, false, false, false, 1><<<dim3((UVW_ + 255) / 256, (B_ * N_) / 256), 512, 0, stream>>>(
            nullptr, featb16, uvwt, nullptr, uv, nullptr, B_ * N_, UVW_, OUT_, zbuf,
            nullptr, nullptr);
        const int PF_BLK = (NPAN * MRC * 8) / 256;
        for (int b0 = 0; b0 < B_; b0 += CBh) {
            pair_fuse_kp<<<PF_BLK, 256, 0, stream>>>(uv, h_b1, src0, dst0, p1k,
                                                     b0, RSH);
            mfma_gemm_k<3, false, true, false, true, 1><<<dim3(2, MRC / 256), 512, 0, stream>>>(
                nullptr, p1k, hw2t, h_b2, nullptr, nullptr, MRC, OUT_, PAIR_, zbuf,
                h_w3, part);
            red3_k<<<(MRC + 255) / 256, 256, 0, stream>>>(part, h_b3, out,
                                                          b0 * E_, MRC, 2);
        }
    } else {
        for (int b = 0; b < B_; ++b) {
            const float* featb = feat + (size_t)b * N_ * OUT_;
            mfma_gemm_k<0, false, false, false, false, 0><<<dim3((UVW_ + 127) / 128, N_ / 128), 256, 0, stream>>>(
                featb, nullptr, uvwt, nullptr, uv, nullptr, N_, UVW_, OUT_, zbuf,
                nullptr, nullptr);
            pair_fuse_k<<<(E_ * 100 + 255) / 256, 256, 0, stream>>>(
                uv, h_b1, src0, dst0, p1, -1, E_);
            mfma_gemm_k<1, true, true, false, false, 0><<<dim3((OUT_ + 127) / 128, E_ / 128), 256, 0, stream>>>(
                nullptr, p1, hw2t, h_b2, p2, nullptr, E_, OUT_, PAIR_, zbuf,
                nullptr, nullptr);
            head3_k<<<(E_ + 15) / 16, 256, 0, stream>>>(p2, h_w3, h_b3, out,
                                                        b * E_, E_);
        }
    }
}